// Round 2
// baseline (1477.876 us; speedup 1.0000x reference)
//
#include <hip/hip_runtime.h>

typedef unsigned short u16;
using bf16x8 = __attribute__((ext_vector_type(8))) __bf16;
using f32x4  = __attribute__((ext_vector_type(4))) float;

__device__ __forceinline__ u16 f2b(float f) {
    unsigned u = __float_as_uint(f);
    u += 0x7fffu + ((u >> 16) & 1u);   // round-to-nearest-even
    return (u16)(u >> 16);
}
__device__ __forceinline__ float b2f(u16 h) {
    return __uint_as_float(((unsigned)h) << 16);
}

// async global->LDS, 16B per lane; LDS dest = wave-uniform base + lane*16
__device__ __forceinline__ void gl2lds16(const void* g, void* l) {
    __builtin_amdgcn_global_load_lds(
        (const __attribute__((address_space(1))) void*)g,
        (__attribute__((address_space(3))) void*)l, 16, 0, 0);
}

// ---------------------------------------------------------------- elementwise
__global__ __launch_bounds__(256) void cast_bf16_kernel(
        const float4* __restrict__ src, ushort4* __restrict__ dst, int n4) {
    int i = blockIdx.x * 256 + threadIdx.x;
    if (i < n4) {
        float4 v = src[i];
        ushort4 o; o.x = f2b(v.x); o.y = f2b(v.y); o.z = f2b(v.z); o.w = f2b(v.w);
        dst[i] = o;
    }
}

__global__ __launch_bounds__(256) void prec2_kernel(
        const float* __restrict__ lp, float* __restrict__ p2, int n) {
    int i = blockIdx.x * 256 + threadIdx.x;
    if (i < n) {
        float v = lp[i];
        float sp = fmaxf(v, 0.f) + log1pf(expf(-fabsf(v)));   // stable softplus
        p2[i] = sp * sp;
    }
}

// src[R][C] f32 -> dst[C][R] bf16, optionally scaled by scale[src_row]
__global__ __launch_bounds__(256) void transpose_cast_kernel(
        const float* __restrict__ src, u16* __restrict__ dst, int R, int C,
        const float* __restrict__ scale) {
    __shared__ float tile[32][33];
    const int bx = blockIdx.x * 32;      // col block in src
    const int by = blockIdx.y * 32;      // row block in src
    const int tx = threadIdx.x & 31;
    const int ty = threadIdx.x >> 5;     // 0..7
#pragma unroll
    for (int i = 0; i < 32; i += 8) {
        float s = scale ? scale[by + ty + i] : 1.f;
        tile[ty + i][tx] = s * src[(size_t)(by + ty + i) * C + (bx + tx)];
    }
    __syncthreads();
#pragma unroll
    for (int i = 0; i < 32; i += 8)
        dst[(size_t)(bx + ty + i) * R + (by + tx)] = f2b(tile[tx][ty + i]);
}

// cvec[j] = sum_i gb[i] * DGt[j][i]; one wave per j
__global__ __launch_bounds__(256) void cvec_kernel(
        const float* __restrict__ gb, const u16* __restrict__ DGt,
        float* __restrict__ cv, int in) {
    const int j = blockIdx.x * 4 + (threadIdx.x >> 6);
    const int lane = threadIdx.x & 63;
    const u16* row = DGt + (size_t)j * in;
    float s = 0.f;
    for (int i = lane; i < in; i += 64) s += gb[i] * b2f(row[i]);
#pragma unroll
    for (int off = 32; off > 0; off >>= 1) s += __shfl_down(s, off);
    if (lane == 0) cv[j] = s;
}

// ---------------------------------------------------------------- layernorm
template <int F32OUT>
__global__ __launch_bounds__(256) void ln_kernel(
        const float* __restrict__ T, const float* __restrict__ g,
        const float* __restrict__ b, void* __restrict__ outp, int D) {
    const int row = blockIdx.x;
    const int tid = threadIdx.x;
    const int nv  = D >> 2;
    const float4* rp = (const float4*)(T + (size_t)row * D);

    float4 vals[2];
    float s = 0.f, sq = 0.f;
    int cnt = 0;
    for (int i = tid; i < nv; i += 256) {
        float4 v = rp[i];
        vals[cnt++] = v;
        s  += v.x + v.y + v.z + v.w;
        sq += v.x * v.x + v.y * v.y + v.z * v.z + v.w * v.w;
    }
#pragma unroll
    for (int off = 32; off > 0; off >>= 1) {
        s  += __shfl_down(s, off);
        sq += __shfl_down(sq, off);
    }
    __shared__ float ssum[4], ssq[4];
    if ((tid & 63) == 0) { ssum[tid >> 6] = s; ssq[tid >> 6] = sq; }
    __syncthreads();
    const float ts = ssum[0] + ssum[1] + ssum[2] + ssum[3];
    const float tq = ssq[0] + ssq[1] + ssq[2] + ssq[3];
    const float mu   = ts / (float)D;
    const float rstd = rsqrtf(tq / (float)D - mu * mu + 1e-5f);

    cnt = 0;
    for (int i = tid; i < nv; i += 256) {
        float4 v  = vals[cnt++];
        float4 gg = ((const float4*)g)[i];
        float4 bb = ((const float4*)b)[i];
        float o0 = (v.x - mu) * rstd * gg.x + bb.x;
        float o1 = (v.y - mu) * rstd * gg.y + bb.y;
        float o2 = (v.z - mu) * rstd * gg.z + bb.z;
        float o3 = (v.w - mu) * rstd * gg.w + bb.w;
        if (F32OUT) {
            ((float4*)outp)[(size_t)row * nv + i] = make_float4(o0, o1, o2, o3);
        } else {
            ushort4 o; o.x = f2b(o0); o.y = f2b(o1); o.z = f2b(o2); o.w = f2b(o3);
            ((ushort4*)outp)[(size_t)row * nv + i] = o;
        }
    }
}

// ---------------------------------------------------------------- GEMM epilogues
enum { EPI_BIAS = 0, EPI_CMB = 1, EPI_W = 2, EPI_ITER = 3 };

// ---------------------------------------------------------------- GEMM 128x128 (m97 structure)
// kept for the small W = G^T D G products (better occupancy at 2048^2 / 1024^2)
template <int EPI>
__global__ __launch_bounds__(256) void gemm_bt(
        const u16* __restrict__ A, const u16* __restrict__ Bt, int N, int K,
        const float* __restrict__ bias, const u16* __restrict__ Cc,
        const u16* __restrict__ H, void* __restrict__ outp) {
    __shared__ u16 As[128 * 32];
    __shared__ u16 Bs[128 * 32];

    const int tid  = threadIdx.x;
    const int lane = tid & 63;
    const int wave = tid >> 6;
    const size_t row0 = (size_t)blockIdx.y * 128;
    const size_t col0 = (size_t)blockIdx.x * 128;

    const int sr = tid >> 2;
    const int sc = (tid & 3) * 8;
    const u16* gA0 = A  + (row0 + sr) * K + sc;
    const u16* gA1 = gA0 + (size_t)64 * K;
    const u16* gB0 = Bt + (col0 + sr) * K + sc;
    const u16* gB1 = gB0 + (size_t)64 * K;
    char* lA = (char*)As + wave * 1024;
    char* lB = (char*)Bs + wave * 1024;

    const int wm = wave >> 1, wn = wave & 1;
    const int fr = lane & 15;
    const int fq = lane >> 4;
    const bf16x8* aP[4];
    const bf16x8* bP[4];
#pragma unroll
    for (int i = 0; i < 4; ++i) {
        aP[i] = (const bf16x8*)(As + (wm * 64 + i * 16 + fr) * 32 + fq * 8);
        bP[i] = (const bf16x8*)(Bs + (wn * 64 + i * 16 + fr) * 32 + fq * 8);
    }

    f32x4 acc[4][4];
    const f32x4 zero = {0.f, 0.f, 0.f, 0.f};
#pragma unroll
    for (int i = 0; i < 4; ++i)
#pragma unroll
        for (int j = 0; j < 4; ++j) acc[i][j] = zero;

    for (int k0 = 0; k0 < K; k0 += 32) {
        __syncthreads();
        gl2lds16(gA0, lA);
        gl2lds16(gA1, lA + 4096);
        gl2lds16(gB0, lB);
        gl2lds16(gB1, lB + 4096);
        __syncthreads();
        bf16x8 af[4], bfr[4];
#pragma unroll
        for (int i = 0; i < 4; ++i) { af[i] = *aP[i]; bfr[i] = *bP[i]; }
#pragma unroll
        for (int i = 0; i < 4; ++i)
#pragma unroll
            for (int j = 0; j < 4; ++j)
                acc[i][j] = __builtin_amdgcn_mfma_f32_16x16x32_bf16(
                    af[i], bfr[j], acc[i][j], 0, 0, 0);
        gA0 += 32; gA1 += 32; gB0 += 32; gB1 += 32;
    }

#pragma unroll
    for (int i = 0; i < 4; ++i) {
#pragma unroll
        for (int r = 0; r < 4; ++r) {
            const size_t gr = row0 + wm * 64 + i * 16 + fq * 4 + r;
#pragma unroll
            for (int j = 0; j < 4; ++j) {
                const size_t gc  = col0 + wn * 64 + j * 16 + fr;
                const size_t idx = gr * (size_t)N + gc;
                const float v = acc[i][j][r];
                if (EPI == EPI_BIAS) {
                    ((float*)outp)[idx] = v + bias[gc];
                } else if (EPI == EPI_CMB) {
                    ((u16*)outp)[idx] = f2b(v - bias[gc]);
                } else if (EPI == EPI_W) {
                    ((u16*)outp)[idx] = f2b(v);
                } else {
                    ((float*)outp)[idx] = b2f(H[idx]) + 0.2f * (b2f(Cc[idx]) - v);
                }
            }
        }
    }
}

// ---------------------------------------------------------------- GEMM 256x256, 8-phase
// C[M,N] = A[M,K] (bf16 rm) x Bt[N,K]^T.  512 thr = 8 waves (2Mx4N), BK=64,
// 128 KiB LDS double-buffered.
// LDS swizzle (16B granularity): phys = logical ^ ((row&7) << 4).
//   - staging keeps linear LDS dest (global_load_lds requirement) and pre-swizzles
//     the GLOBAL source column: col16 = (lane&7) ^ (lane>>3)  [issue base rows %8==0]
//   - fragment ds_read XORs (fr&7)<<4 (A rows i*16+fr, B rows (wn&1)*64+fr: row&7==fr&7)
//   - every aligned 8-lane group covers all 8 16B-slots -> conflict-free b128 reads
// counted vmcnt (6 in steady state), setprio around MFMA clusters.
// Requires: M%256==0, N%256==0, K%64==0, K>=128.
template <int EPI>
__global__ __launch_bounds__(512, 2) void gemm256(
        const u16* __restrict__ A, const u16* __restrict__ Bt, int N, int K,
        const float* __restrict__ bias, const u16* __restrict__ Cc,
        const u16* __restrict__ H, void* __restrict__ outp) {
    extern __shared__ char smem[];   // 131072 B: buf b at b*65536; A halves +0,+16K; B halves +32K,+48K

    const int tid  = threadIdx.x;
    const int lane = tid & 63;
    const int w    = tid >> 6;       // 0..7
    const int wm   = w >> 2;         // 0..1
    const int wn   = w & 3;          // 0..3
    const int fr   = lane & 15;
    const int fq   = lane >> 4;      // 0..3

    // bijective XCD-aware block swizzle (all launches have nwg % 8 == 0)
    const int nwg = gridDim.x * gridDim.y;
    const int bid = blockIdx.y * gridDim.x + blockIdx.x;
    int sbid = bid;
    if (!(nwg & 7)) sbid = (bid & 7) * (nwg >> 3) + (bid >> 3);
    const int bx = sbid % gridDim.x;
    const int by = sbid / gridDim.x;
    const size_t row0 = (size_t)by * 256;
    const size_t col0 = (size_t)bx * 256;

    // ---- staging: pre-swizzled global source so linear LDS writes land swizzled.
    // lane l covers row (base + l>>3), phys bytes (l&7)*16; logical col16 = (l&7)^(l>>3).
    const int scol = ((lane & 7) ^ (lane >> 3)) << 4;
    const char* sA[2][2];
    const char* sB[2][2];
    int dA[2][2], dB[2][2];
#pragma unroll
    for (int h = 0; h < 2; ++h)
#pragma unroll
        for (int g = 0; g < 2; ++g) {
            const size_t rr = (size_t)(h * 128 + g * 64 + w * 8 + (lane >> 3));
            sA[h][g] = (const char*)A  + (row0 + rr) * (size_t)K * 2 + scol;
            sB[h][g] = (const char*)Bt + (col0 + rr) * (size_t)K * 2 + scol;
            dA[h][g] = h * 16384 + (g * 64 + w * 8) * 128;
            dB[h][g] = 32768 + dA[h][g];
        }

    // ---- fragment read offsets: logical byte (within half) = r*128 + s*64 + fq*16,
    // phys = logical ^ ((r&7)<<4); r&7 == fr&7 for both A and B row patterns.
    const int swzR = (fr & 7) << 4;
    int aoff[2], boff[2];
#pragma unroll
    for (int s = 0; s < 2; ++s) {
        aoff[s] = ((fr * 128 + s * 64 + fq * 16) ^ swzR) + wm * 16384;
        boff[s] = ((((wn & 1) * 64 + fr) * 128 + s * 64 + fq * 16) ^ swzR)
                  + 32768 + (wn >> 1) * 16384;
    }

    f32x4 acc[8][4];
    const f32x4 zero = {0.f, 0.f, 0.f, 0.f};
#pragma unroll
    for (int i = 0; i < 8; ++i)
#pragma unroll
        for (int j = 0; j < 4; ++j) acc[i][j] = zero;

    // ---- prologue: stage K-tile 0 -> buf0 (8 issues), K-tile 1 -> buf1 (8 issues)
#pragma unroll
    for (int h = 0; h < 2; ++h)
#pragma unroll
        for (int g = 0; g < 2; ++g) {
            gl2lds16(sA[h][g], smem + dA[h][g]);
            gl2lds16(sB[h][g], smem + dB[h][g]);
        }
    __builtin_amdgcn_sched_barrier(0);
#pragma unroll
    for (int h = 0; h < 2; ++h)
#pragma unroll
        for (int g = 0; g < 2; ++g) {
            gl2lds16(sA[h][g] + 128, smem + 65536 + dA[h][g]);
            gl2lds16(sB[h][g] + 128, smem + 65536 + dB[h][g]);
        }
    asm volatile("s_waitcnt vmcnt(8)");            // tile 0 resident; tile 1 in flight
    __builtin_amdgcn_sched_barrier(0);
    __builtin_amdgcn_s_barrier();
    __builtin_amdgcn_sched_barrier(0);

    const int T = K >> 6;
    for (int t = 0; t < T; ++t) {
        const char* base = smem + ((t & 1) << 16);
        const int kb = (t + 2) * 128;              // byte offset of tile t+2 in global rows
        bf16x8 a[8][2], b[4][2];

        // ===== phase 0: read A[0-3],B[0-1]; MFMA Q(0,0)
#pragma unroll
        for (int i = 0; i < 4; ++i)
#pragma unroll
            for (int s = 0; s < 2; ++s)
                a[i][s] = *(const bf16x8*)(base + aoff[s] + i * 2048);
#pragma unroll
        for (int j = 0; j < 2; ++j)
#pragma unroll
            for (int s = 0; s < 2; ++s)
                b[j][s] = *(const bf16x8*)(base + boff[s] + j * 2048);
        __builtin_amdgcn_sched_barrier(0);
        __builtin_amdgcn_s_barrier();
        asm volatile("s_waitcnt lgkmcnt(0)");
        __builtin_amdgcn_sched_barrier(0);
        __builtin_amdgcn_s_setprio(1);
#pragma unroll
        for (int i = 0; i < 4; ++i)
#pragma unroll
            for (int j = 0; j < 2; ++j)
#pragma unroll
                for (int s = 0; s < 2; ++s)
                    acc[i][j] = __builtin_amdgcn_mfma_f32_16x16x32_bf16(
                        a[i][s], b[j][s], acc[i][j], 0, 0, 0);
        __builtin_amdgcn_s_setprio(0);
        __builtin_amdgcn_sched_barrier(0);
        __builtin_amdgcn_s_barrier();
        __builtin_amdgcn_sched_barrier(0);

        // ===== phase 1: read A[4-7]; MFMA Q(1,0)
#pragma unroll
        for (int i = 4; i < 8; ++i)
#pragma unroll
            for (int s = 0; s < 2; ++s)
                a[i][s] = *(const bf16x8*)(base + aoff[s] + i * 2048);
        __builtin_amdgcn_sched_barrier(0);
        __builtin_amdgcn_s_barrier();
        asm volatile("s_waitcnt lgkmcnt(0)");
        __builtin_amdgcn_sched_barrier(0);
        __builtin_amdgcn_s_setprio(1);
#pragma unroll
        for (int i = 4; i < 8; ++i)
#pragma unroll
            for (int j = 0; j < 2; ++j)
#pragma unroll
                for (int s = 0; s < 2; ++s)
                    acc[i][j] = __builtin_amdgcn_mfma_f32_16x16x32_bf16(
                        a[i][s], b[j][s], acc[i][j], 0, 0, 0);
        __builtin_amdgcn_s_setprio(0);
        __builtin_amdgcn_sched_barrier(0);
        __builtin_amdgcn_s_barrier();
        __builtin_amdgcn_sched_barrier(0);

        // ===== phase 2: read B[2-3]; stage A halves of tile t+2 (A of this buf is
        // fully read as of phase 1's end barrier); MFMA Q(0,1)
#pragma unroll
        for (int j = 2; j < 4; ++j)
#pragma unroll
            for (int s = 0; s < 2; ++s)
                b[j][s] = *(const bf16x8*)(base + boff[s] + j * 2048);
        if (t + 2 < T) {
#pragma unroll
            for (int h = 0; h < 2; ++h)
#pragma unroll
                for (int g = 0; g < 2; ++g)
                    gl2lds16(sA[h][g] + kb, smem + ((t & 1) << 16) + dA[h][g]);
        }
        __builtin_amdgcn_sched_barrier(0);
        __builtin_amdgcn_s_barrier();
        asm volatile("s_waitcnt lgkmcnt(0)");
        __builtin_amdgcn_sched_barrier(0);
        __builtin_amdgcn_s_setprio(1);
#pragma unroll
        for (int i = 0; i < 4; ++i)
#pragma unroll
            for (int j = 2; j < 4; ++j)
#pragma unroll
                for (int s = 0; s < 2; ++s)
                    acc[i][j] = __builtin_amdgcn_mfma_f32_16x16x32_bf16(
                        a[i][s], b[j][s], acc[i][j], 0, 0, 0);
        __builtin_amdgcn_s_setprio(0);
        __builtin_amdgcn_sched_barrier(0);
        __builtin_amdgcn_s_barrier();
        __builtin_amdgcn_sched_barrier(0);

        // ===== phase 3: stage B halves of tile t+2 (B fully read as of phase 2's end
        // barrier); MFMA Q(1,1); counted vmcnt before end barrier (never 0 mid-loop)
        if (t + 2 < T) {
#pragma unroll
            for (int h = 0; h < 2; ++h)
#pragma unroll
                for (int g = 0; g < 2; ++g)
                    gl2lds16(sB[h][g] + kb, smem + ((t & 1) << 16) + dB[h][g]);
        }
        __builtin_amdgcn_sched_barrier(0);
        __builtin_amdgcn_s_barrier();
        asm volatile("s_waitcnt lgkmcnt(0)");
        __builtin_amdgcn_sched_barrier(0);
        __builtin_amdgcn_s_setprio(1);
#pragma unroll
        for (int i = 4; i < 8; ++i)
#pragma unroll
            for (int j = 2; j < 4; ++j)
#pragma unroll
                for (int s = 0; s < 2; ++s)
                    acc[i][j] = __builtin_amdgcn_mfma_f32_16x16x32_bf16(
                        a[i][s], b[j][s], acc[i][j], 0, 0, 0);
        __builtin_amdgcn_s_setprio(0);
        __builtin_amdgcn_sched_barrier(0);
        if (t + 2 < T) {
            // drains tile t+1 fully (+ oldest HT of t+2); leaves 3 HTs (6 loads) in flight
            asm volatile("s_waitcnt vmcnt(6)");
        } else if (t + 2 == T) {
            asm volatile("s_waitcnt vmcnt(0)");    // last prefetched tile fully resident
        }
        __builtin_amdgcn_sched_barrier(0);
        __builtin_amdgcn_s_barrier();
        __builtin_amdgcn_sched_barrier(0);
    }

    // ---- epilogue: C/D layout col = lane&15, row = (lane>>4)*4 + reg
#pragma unroll
    for (int i = 0; i < 8; ++i) {
#pragma unroll
        for (int r = 0; r < 4; ++r) {
            const size_t gr = row0 + wm * 128 + i * 16 + fq * 4 + r;
#pragma unroll
            for (int j = 0; j < 4; ++j) {
                const size_t gc  = col0 + wn * 64 + j * 16 + fr;
                const size_t idx = gr * (size_t)N + gc;
                const float v = acc[i][j][r];
                if (EPI == EPI_BIAS) {
                    ((float*)outp)[idx] = v + bias[gc];
                } else if (EPI == EPI_CMB) {
                    ((u16*)outp)[idx] = f2b(v - bias[gc]);
                } else if (EPI == EPI_W) {
                    ((u16*)outp)[idx] = f2b(v);
                } else {
                    ((float*)outp)[idx] = b2f(H[idx]) + 0.2f * (b2f(Cc[idx]) - v);
                }
            }
        }
    }
}

// ---------------------------------------------------------------- host
extern "C" void kernel_launch(void* const* d_in, const int* in_sizes, int n_in,
                              void* d_out, int out_size, void* d_ws, size_t ws_size,
                              hipStream_t stream) {
    const int B = 8192;
    const float* x      = (const float*)d_in[0];
    const float* gen_w0 = (const float*)d_in[1];
    const float* gen_b0 = (const float*)d_in[2];
    const float* rec_w0 = (const float*)d_in[3];
    const float* rec_b0 = (const float*)d_in[4];
    const float* log_p0 = (const float*)d_in[5];
    const float* ln_g0  = (const float*)d_in[6];
    const float* ln_b0  = (const float*)d_in[7];
    const float* gen_w1 = (const float*)d_in[8];
    const float* gen_b1 = (const float*)d_in[9];
    const float* rec_w1 = (const float*)d_in[10];
    const float* rec_b1 = (const float*)d_in[11];
    const float* log_p1 = (const float*)d_in[12];
    const float* ln_g1  = (const float*)d_in[13];
    const float* ln_b1  = (const float*)d_in[14];

    char* ws = (char*)d_ws;
    auto alloc = [&](size_t bytes) -> char* {
        char* p = ws;
        ws += (bytes + 255) & ~(size_t)255;
        return p;
    };
    u16*   Xb   = (u16*)  alloc((size_t)B * 4096 * 2);   // x bf16; L1-prep region after c0
    float* Tf   = (float*)alloc((size_t)B * 2048 * 4);   // pre-LN fp32
    u16*   Hb0  = (u16*)  alloc((size_t)B * 2048 * 2);
    u16*   Cb0  = (u16*)  alloc((size_t)B * 2048 * 2);   // c0 bf16; Gt0 during pre-pass
    u16*   rwb0 = (u16*)  alloc((size_t)2048 * 4096 * 2);
    u16*   DGt0 = (u16*)  alloc((size_t)2048 * 4096 * 2);// Hb1 after c0
    u16*   W0   = (u16*)  alloc((size_t)2048 * 2048 * 2);
    float* p20  = (float*)alloc(4096 * 4);
    float* p21  = (float*)alloc(2048 * 4);
    float* cv0  = (float*)alloc(2048 * 4);
    float* cv1  = (float*)alloc(1024 * 4);

    u16* Gt0 = Cb0;                       // [2048,4096] fits in Cb0
    u16* Hb1 = DGt0;                      // [8192,1024] == DGt0 size
    char* l1 = (char*)Xb;
    u16* rwb1 = (u16*)l1;                 l1 += (size_t)1024 * 2048 * 2;
    u16* Gt1  = (u16*)l1;                 l1 += (size_t)1024 * 2048 * 2;
    u16* DGt1 = (u16*)l1;                 l1 += (size_t)1024 * 2048 * 2;
    u16* W1   = (u16*)l1;                 l1 += (size_t)1024 * 1024 * 2;
    u16* Cb1  = (u16*)l1;                 l1 += (size_t)B * 1024 * 2;

    auto cast = [&](const float* s, u16* d, size_t n) {
        int n4 = (int)(n >> 2);
        cast_bf16_kernel<<<dim3((n4 + 255) / 256), dim3(256), 0, stream>>>(
            (const float4*)s, (ushort4*)d, n4);
    };
    const dim3 blk(256);
    const dim3 blk8(512);
    const size_t LDS8 = 131072;

    // ---- pre-pass (layer 0)
    prec2_kernel<<<dim3(16), blk, 0, stream>>>(log_p0, p20, 4096);
    prec2_kernel<<<dim3(8),  blk, 0, stream>>>(log_p1, p21, 2048);
    cast(x, Xb, (size_t)B * 4096);
    cast(rec_w0, rwb0, (size_t)2048 * 4096);
    transpose_cast_kernel<<<dim3(2048 / 32, 4096 / 32), blk, 0, stream>>>(
        gen_w0, Gt0, 4096, 2048, nullptr);           // Gt0[j][i] = G0[i][j]
    transpose_cast_kernel<<<dim3(2048 / 32, 4096 / 32), blk, 0, stream>>>(
        gen_w0, DGt0, 4096, 2048, p20);              // DGt0[j][i] = p2[i]*G0[i][j]
    cvec_kernel<<<dim3(2048 / 4), blk, 0, stream>>>(gen_b0, DGt0, cv0, 4096);
    // W0 = G0^T D G0  [2048,2048] bf16 (symmetric) — keep 128^2 kernel (occupancy)
    gemm_bt<EPI_W><<<dim3(16, 16), blk, 0, stream>>>(
        Gt0, DGt0, 2048, 4096, nullptr, nullptr, nullptr, W0);

    // ---- layer 0 (in=4096, hid=2048)
    gemm256<EPI_BIAS><<<dim3(8, 32), blk8, LDS8, stream>>>(
        Xb, rwb0, 2048, 4096, rec_b0, nullptr, nullptr, Tf);
    ln_kernel<0><<<dim3(B), blk, 0, stream>>>(Tf, ln_g0, ln_b0, Hb0, 2048);
    // c0 = x @ (D G0) - cv0   (last use of Xb, Gt0/Cb0 free after this writes)
    gemm256<EPI_CMB><<<dim3(8, 32), blk8, LDS8, stream>>>(
        Xb, DGt0, 2048, 4096, cv0, nullptr, nullptr, Cb0);

    // ---- L1 prep (overwrites Xb region; DGt0 still live until here — done)
    cast(rec_w1, rwb1, (size_t)1024 * 2048);
    transpose_cast_kernel<<<dim3(1024 / 32, 2048 / 32), blk, 0, stream>>>(
        gen_w1, Gt1, 2048, 1024, nullptr);
    transpose_cast_kernel<<<dim3(1024 / 32, 2048 / 32), blk, 0, stream>>>(
        gen_w1, DGt1, 2048, 1024, p21);
    cvec_kernel<<<dim3(1024 / 4), blk, 0, stream>>>(gen_b1, DGt1, cv1, 2048);
    gemm_bt<EPI_W><<<dim3(8, 8), blk, 0, stream>>>(
        Gt1, DGt1, 1024, 2048, nullptr, nullptr, nullptr, W1);

    // ---- layer 0 iterations: T = h + 0.2*(c0 - h@W0); h = LN(T)
    for (int it = 0; it < 3; ++it) {
        gemm256<EPI_ITER><<<dim3(8, 32), blk8, LDS8, stream>>>(
            Hb0, W0, 2048, 2048, nullptr, Cb0, Hb0, Tf);
        ln_kernel<0><<<dim3(B), blk, 0, stream>>>(Tf, ln_g0, ln_b0, Hb0, 2048);
    }

    // ---- layer 1 (in=2048, hid=1024); input = Hb0 (bf16)
    gemm256<EPI_BIAS><<<dim3(4, 32), blk8, LDS8, stream>>>(
        Hb0, rwb1, 1024, 2048, rec_b1, nullptr, nullptr, Tf);
    ln_kernel<0><<<dim3(B), blk, 0, stream>>>(Tf, ln_g1, ln_b1, Hb1, 1024);
    gemm256<EPI_CMB><<<dim3(4, 32), blk8, LDS8, stream>>>(
        Hb0, DGt1, 1024, 2048, cv1, nullptr, nullptr, Cb1);
    for (int it = 0; it < 3; ++it) {
        gemm256<EPI_ITER><<<dim3(4, 32), blk8, LDS8, stream>>>(
            Hb1, W1, 1024, 1024, nullptr, Cb1, Hb1, Tf);
        if (it < 2)
            ln_kernel<0><<<dim3(B), blk, 0, stream>>>(Tf, ln_g1, ln_b1, Hb1, 1024);
        else
            ln_kernel<1><<<dim3(B), blk, 0, stream>>>(Tf, ln_g1, ln_b1, d_out, 1024);
    }
}

// Round 3
// 1466.626 us; speedup vs baseline: 1.0077x; 1.0077x over previous
//
#include <hip/hip_runtime.h>

typedef unsigned short u16;
using bf16x8 = __attribute__((ext_vector_type(8))) __bf16;
using f32x4  = __attribute__((ext_vector_type(4))) float;

__device__ __forceinline__ u16 f2b(float f) {
    unsigned u = __float_as_uint(f);
    u += 0x7fffu + ((u >> 16) & 1u);   // round-to-nearest-even
    return (u16)(u >> 16);
}
__device__ __forceinline__ float b2f(u16 h) {
    return __uint_as_float(((unsigned)h) << 16);
}

// async global->LDS, 16B per lane; LDS dest = wave-uniform base + lane*16
__device__ __forceinline__ void gl2lds16(const void* g, void* l) {
    __builtin_amdgcn_global_load_lds(
        (const __attribute__((address_space(1))) void*)g,
        (__attribute__((address_space(3))) void*)l, 16, 0, 0);
}

// ---------------------------------------------------------------- elementwise
__global__ __launch_bounds__(256) void cast_bf16_kernel(
        const float4* __restrict__ src, ushort4* __restrict__ dst, int n4) {
    int i = blockIdx.x * 256 + threadIdx.x;
    if (i < n4) {
        float4 v = src[i];
        ushort4 o; o.x = f2b(v.x); o.y = f2b(v.y); o.z = f2b(v.z); o.w = f2b(v.w);
        dst[i] = o;
    }
}

__global__ __launch_bounds__(256) void prec2_kernel(
        const float* __restrict__ lp, float* __restrict__ p2, int n) {
    int i = blockIdx.x * 256 + threadIdx.x;
    if (i < n) {
        float v = lp[i];
        float sp = fmaxf(v, 0.f) + log1pf(expf(-fabsf(v)));   // stable softplus
        p2[i] = sp * sp;
    }
}

// src[R][C] f32 -> dst[C][R] bf16, optionally scaled by scale[src_row]
__global__ __launch_bounds__(256) void transpose_cast_kernel(
        const float* __restrict__ src, u16* __restrict__ dst, int R, int C,
        const float* __restrict__ scale) {
    __shared__ float tile[32][33];
    const int bx = blockIdx.x * 32;      // col block in src
    const int by = blockIdx.y * 32;      // row block in src
    const int tx = threadIdx.x & 31;
    const int ty = threadIdx.x >> 5;     // 0..7
#pragma unroll
    for (int i = 0; i < 32; i += 8) {
        float s = scale ? scale[by + ty + i] : 1.f;
        tile[ty + i][tx] = s * src[(size_t)(by + ty + i) * C + (bx + tx)];
    }
    __syncthreads();
#pragma unroll
    for (int i = 0; i < 32; i += 8)
        dst[(size_t)(bx + ty + i) * R + (by + tx)] = f2b(tile[tx][ty + i]);
}

// cvec[j] = sum_i gb[i] * DGt[j][i]; one wave per j
__global__ __launch_bounds__(256) void cvec_kernel(
        const float* __restrict__ gb, const u16* __restrict__ DGt,
        float* __restrict__ cv, int in) {
    const int j = blockIdx.x * 4 + (threadIdx.x >> 6);
    const int lane = threadIdx.x & 63;
    const u16* row = DGt + (size_t)j * in;
    float s = 0.f;
    for (int i = lane; i < in; i += 64) s += gb[i] * b2f(row[i]);
#pragma unroll
    for (int off = 32; off > 0; off >>= 1) s += __shfl_down(s, off);
    if (lane == 0) cv[j] = s;
}

// ---------------------------------------------------------------- layernorm
template <int F32OUT>
__global__ __launch_bounds__(256) void ln_kernel(
        const float* __restrict__ T, const float* __restrict__ g,
        const float* __restrict__ b, void* __restrict__ outp, int D) {
    const int row = blockIdx.x;
    const int tid = threadIdx.x;
    const int nv  = D >> 2;
    const float4* rp = (const float4*)(T + (size_t)row * D);

    float4 vals[2];
    float s = 0.f, sq = 0.f;
    int cnt = 0;
    for (int i = tid; i < nv; i += 256) {
        float4 v = rp[i];
        vals[cnt++] = v;
        s  += v.x + v.y + v.z + v.w;
        sq += v.x * v.x + v.y * v.y + v.z * v.z + v.w * v.w;
    }
#pragma unroll
    for (int off = 32; off > 0; off >>= 1) {
        s  += __shfl_down(s, off);
        sq += __shfl_down(sq, off);
    }
    __shared__ float ssum[4], ssq[4];
    if ((tid & 63) == 0) { ssum[tid >> 6] = s; ssq[tid >> 6] = sq; }
    __syncthreads();
    const float ts = ssum[0] + ssum[1] + ssum[2] + ssum[3];
    const float tq = ssq[0] + ssq[1] + ssq[2] + ssq[3];
    const float mu   = ts / (float)D;
    const float rstd = rsqrtf(tq / (float)D - mu * mu + 1e-5f);

    cnt = 0;
    for (int i = tid; i < nv; i += 256) {
        float4 v  = vals[cnt++];
        float4 gg = ((const float4*)g)[i];
        float4 bb = ((const float4*)b)[i];
        float o0 = (v.x - mu) * rstd * gg.x + bb.x;
        float o1 = (v.y - mu) * rstd * gg.y + bb.y;
        float o2 = (v.z - mu) * rstd * gg.z + bb.z;
        float o3 = (v.w - mu) * rstd * gg.w + bb.w;
        if (F32OUT) {
            ((float4*)outp)[(size_t)row * nv + i] = make_float4(o0, o1, o2, o3);
        } else {
            ushort4 o; o.x = f2b(o0); o.y = f2b(o1); o.z = f2b(o2); o.w = f2b(o3);
            ((ushort4*)outp)[(size_t)row * nv + i] = o;
        }
    }
}

// ---------------------------------------------------------------- GEMM epilogues
enum { EPI_BIAS = 0, EPI_CMB = 1, EPI_W = 2, EPI_ITER = 3 };

// ---------------------------------------------------------------- GEMM 128x128 (m97 structure)
// kept for the small W = G^T D G products (better occupancy at 2048^2 / 1024^2)
template <int EPI>
__global__ __launch_bounds__(256) void gemm_bt(
        const u16* __restrict__ A, const u16* __restrict__ Bt, int N, int K,
        const float* __restrict__ bias, const u16* __restrict__ Cc,
        const u16* __restrict__ H, void* __restrict__ outp) {
    __shared__ u16 As[128 * 32];
    __shared__ u16 Bs[128 * 32];

    const int tid  = threadIdx.x;
    const int lane = tid & 63;
    const int wave = tid >> 6;
    const size_t row0 = (size_t)blockIdx.y * 128;
    const size_t col0 = (size_t)blockIdx.x * 128;

    const int sr = tid >> 2;
    const int sc = (tid & 3) * 8;
    const u16* gA0 = A  + (row0 + sr) * K + sc;
    const u16* gA1 = gA0 + (size_t)64 * K;
    const u16* gB0 = Bt + (col0 + sr) * K + sc;
    const u16* gB1 = gB0 + (size_t)64 * K;
    char* lA = (char*)As + wave * 1024;
    char* lB = (char*)Bs + wave * 1024;

    const int wm = wave >> 1, wn = wave & 1;
    const int fr = lane & 15;
    const int fq = lane >> 4;
    const bf16x8* aP[4];
    const bf16x8* bP[4];
#pragma unroll
    for (int i = 0; i < 4; ++i) {
        aP[i] = (const bf16x8*)(As + (wm * 64 + i * 16 + fr) * 32 + fq * 8);
        bP[i] = (const bf16x8*)(Bs + (wn * 64 + i * 16 + fr) * 32 + fq * 8);
    }

    f32x4 acc[4][4];
    const f32x4 zero = {0.f, 0.f, 0.f, 0.f};
#pragma unroll
    for (int i = 0; i < 4; ++i)
#pragma unroll
        for (int j = 0; j < 4; ++j) acc[i][j] = zero;

    for (int k0 = 0; k0 < K; k0 += 32) {
        __syncthreads();
        gl2lds16(gA0, lA);
        gl2lds16(gA1, lA + 4096);
        gl2lds16(gB0, lB);
        gl2lds16(gB1, lB + 4096);
        __syncthreads();
        bf16x8 af[4], bfr[4];
#pragma unroll
        for (int i = 0; i < 4; ++i) { af[i] = *aP[i]; bfr[i] = *bP[i]; }
#pragma unroll
        for (int i = 0; i < 4; ++i)
#pragma unroll
            for (int j = 0; j < 4; ++j)
                acc[i][j] = __builtin_amdgcn_mfma_f32_16x16x32_bf16(
                    af[i], bfr[j], acc[i][j], 0, 0, 0);
        gA0 += 32; gA1 += 32; gB0 += 32; gB1 += 32;
    }

#pragma unroll
    for (int i = 0; i < 4; ++i) {
#pragma unroll
        for (int r = 0; r < 4; ++r) {
            const size_t gr = row0 + wm * 64 + i * 16 + fq * 4 + r;
#pragma unroll
            for (int j = 0; j < 4; ++j) {
                const size_t gc  = col0 + wn * 64 + j * 16 + fr;
                const size_t idx = gr * (size_t)N + gc;
                const float v = acc[i][j][r];
                if (EPI == EPI_BIAS) {
                    ((float*)outp)[idx] = v + bias[gc];
                } else if (EPI == EPI_CMB) {
                    ((u16*)outp)[idx] = f2b(v - bias[gc]);
                } else if (EPI == EPI_W) {
                    ((u16*)outp)[idx] = f2b(v);
                } else {
                    ((float*)outp)[idx] = b2f(H[idx]) + 0.2f * (b2f(Cc[idx]) - v);
                }
            }
        }
    }
}

// ---------------------------------------------------------------- GEMM 256x256, 8-phase
// C[M,N] = A[M,K] (bf16 rm) x Bt[N,K]^T.  512 thr = 8 waves (2Mx4N), BK=64,
// 128 KiB LDS double-buffered.
// LDS swizzle (16B granularity): phys = logical ^ ((row&7) << 4), both-sides (rule #21).
// Fragment reads are SOFTWARE-PIPELINED across phases: all 24 ds_read_b128 issue at
// tile start in order [a0-3(8) b0-1(4) a4-7(8) b2-3(4)]; phases wait with counted
// lgkmcnt (12/4/0/-) so the read drain overlaps the MFMA clusters.
// Hazards: A-staging (ph2) after ph1-end barrier (all waves drained a-reads via
// lgkmcnt(4)); B-staging (ph3) after ph2-end barrier (lgkmcnt(0)); tile RAW via
// counted vmcnt(6) + tile-end barrier (never drained to 0 mid-loop).
// Requires: M%256==0, N%256==0, K%64==0, K>=128.
template <int EPI>
__global__ __launch_bounds__(512, 2) void gemm256(
        const u16* __restrict__ A, const u16* __restrict__ Bt, int N, int K,
        const float* __restrict__ bias, const u16* __restrict__ Cc,
        const u16* __restrict__ H, void* __restrict__ outp) {
    extern __shared__ char smem[];   // 131072 B: buf b at b*65536; A halves +0,+16K; B halves +32K,+48K

    const int tid  = threadIdx.x;
    const int lane = tid & 63;
    const int w    = tid >> 6;       // 0..7
    const int wm   = w >> 2;         // 0..1
    const int wn   = w & 3;          // 0..3
    const int fr   = lane & 15;
    const int fq   = lane >> 4;      // 0..3

    // bijective XCD-aware block swizzle (all launches have nwg % 8 == 0)
    const int nwg = gridDim.x * gridDim.y;
    const int bid = blockIdx.y * gridDim.x + blockIdx.x;
    int sbid = bid;
    if (!(nwg & 7)) sbid = (bid & 7) * (nwg >> 3) + (bid >> 3);
    const int bx = sbid % gridDim.x;
    const int by = sbid / gridDim.x;
    const size_t row0 = (size_t)by * 256;
    const size_t col0 = (size_t)bx * 256;

    // ---- staging: pre-swizzled global source so linear LDS writes land swizzled.
    // lane l covers row (base + l>>3), phys bytes (l&7)*16; logical col16 = (l&7)^(l>>3).
    const int scol = ((lane & 7) ^ (lane >> 3)) << 4;
    const char* sA[2][2];
    const char* sB[2][2];
    int dA[2][2], dB[2][2];
#pragma unroll
    for (int h = 0; h < 2; ++h)
#pragma unroll
        for (int g = 0; g < 2; ++g) {
            const size_t rr = (size_t)(h * 128 + g * 64 + w * 8 + (lane >> 3));
            sA[h][g] = (const char*)A  + (row0 + rr) * (size_t)K * 2 + scol;
            sB[h][g] = (const char*)Bt + (col0 + rr) * (size_t)K * 2 + scol;
            dA[h][g] = h * 16384 + (g * 64 + w * 8) * 128;
            dB[h][g] = 32768 + dA[h][g];
        }

    // ---- fragment read offsets: logical byte (within half) = r*128 + s*64 + fq*16,
    // phys = logical ^ ((r&7)<<4); r&7 == fr&7 for both A and B row patterns.
    const int swzR = (fr & 7) << 4;
    int aoff[2], boff[2];
#pragma unroll
    for (int s = 0; s < 2; ++s) {
        aoff[s] = ((fr * 128 + s * 64 + fq * 16) ^ swzR) + wm * 16384;
        boff[s] = ((((wn & 1) * 64 + fr) * 128 + s * 64 + fq * 16) ^ swzR)
                  + 32768 + (wn >> 1) * 16384;
    }

    f32x4 acc[8][4];
    const f32x4 zero = {0.f, 0.f, 0.f, 0.f};
#pragma unroll
    for (int i = 0; i < 8; ++i)
#pragma unroll
        for (int j = 0; j < 4; ++j) acc[i][j] = zero;

    // ---- prologue: stage K-tile 0 -> buf0 (8 issues), K-tile 1 -> buf1 (8 issues)
#pragma unroll
    for (int h = 0; h < 2; ++h)
#pragma unroll
        for (int g = 0; g < 2; ++g) {
            gl2lds16(sA[h][g], smem + dA[h][g]);
            gl2lds16(sB[h][g], smem + dB[h][g]);
        }
    __builtin_amdgcn_sched_barrier(0);
#pragma unroll
    for (int h = 0; h < 2; ++h)
#pragma unroll
        for (int g = 0; g < 2; ++g) {
            gl2lds16(sA[h][g] + 128, smem + 65536 + dA[h][g]);
            gl2lds16(sB[h][g] + 128, smem + 65536 + dB[h][g]);
        }
    asm volatile("s_waitcnt vmcnt(8)");            // tile 0 resident; tile 1 in flight
    __builtin_amdgcn_sched_barrier(0);
    __builtin_amdgcn_s_barrier();
    __builtin_amdgcn_sched_barrier(0);

    const int T = K >> 6;
    for (int t = 0; t < T; ++t) {
        const char* base = smem + ((t & 1) << 16);
        const int kb = (t + 2) * 128;              // byte offset of tile t+2 in global rows
        bf16x8 a[8][2], b[4][2];

        // ---- issue ALL fragment reads for this tile (in-order LGKM queue):
        // [a0-3 x2 (8)] [b0-1 x2 (4)] [a4-7 x2 (8)] [b2-3 x2 (4)]
#pragma unroll
        for (int i = 0; i < 4; ++i)
#pragma unroll
            for (int s = 0; s < 2; ++s)
                a[i][s] = *(const bf16x8*)(base + aoff[s] + i * 2048);
#pragma unroll
        for (int j = 0; j < 2; ++j)
#pragma unroll
            for (int s = 0; s < 2; ++s)
                b[j][s] = *(const bf16x8*)(base + boff[s] + j * 2048);
#pragma unroll
        for (int i = 4; i < 8; ++i)
#pragma unroll
            for (int s = 0; s < 2; ++s)
                a[i][s] = *(const bf16x8*)(base + aoff[s] + i * 2048);
#pragma unroll
        for (int j = 2; j < 4; ++j)
#pragma unroll
            for (int s = 0; s < 2; ++s)
                b[j][s] = *(const bf16x8*)(base + boff[s] + j * 2048);
        __builtin_amdgcn_sched_barrier(0);
        __builtin_amdgcn_s_barrier();              // tile-start alignment
        __builtin_amdgcn_sched_barrier(0);

        // ===== phase 0: Q(0,0) — needs first 12 reads; 12 newest may stay in flight
        asm volatile("s_waitcnt lgkmcnt(12)");
        __builtin_amdgcn_sched_barrier(0);
        __builtin_amdgcn_s_setprio(1);
#pragma unroll
        for (int i = 0; i < 4; ++i)
#pragma unroll
            for (int j = 0; j < 2; ++j)
#pragma unroll
                for (int s = 0; s < 2; ++s)
                    acc[i][j] = __builtin_amdgcn_mfma_f32_16x16x32_bf16(
                        a[i][s], b[j][s], acc[i][j], 0, 0, 0);
        __builtin_amdgcn_s_setprio(0);
        __builtin_amdgcn_sched_barrier(0);
        __builtin_amdgcn_s_barrier();
        __builtin_amdgcn_sched_barrier(0);

        // ===== phase 1: Q(1,0) — needs a4-7; only b2-3 (4) may stay in flight
        asm volatile("s_waitcnt lgkmcnt(4)");
        __builtin_amdgcn_sched_barrier(0);
        __builtin_amdgcn_s_setprio(1);
#pragma unroll
        for (int i = 4; i < 8; ++i)
#pragma unroll
            for (int j = 0; j < 2; ++j)
#pragma unroll
                for (int s = 0; s < 2; ++s)
                    acc[i][j] = __builtin_amdgcn_mfma_f32_16x16x32_bf16(
                        a[i][s], b[j][s], acc[i][j], 0, 0, 0);
        __builtin_amdgcn_s_setprio(0);
        __builtin_amdgcn_sched_barrier(0);
        __builtin_amdgcn_s_barrier();              // all waves' A-reads complete here
        __builtin_amdgcn_sched_barrier(0);

        // ===== phase 2: stage A halves of tile t+2 (A region now safe); Q(0,1)
        if (t + 2 < T) {
#pragma unroll
            for (int h = 0; h < 2; ++h)
#pragma unroll
                for (int g = 0; g < 2; ++g)
                    gl2lds16(sA[h][g] + kb, smem + ((t & 1) << 16) + dA[h][g]);
        }
        __builtin_amdgcn_sched_barrier(0);
        asm volatile("s_waitcnt lgkmcnt(0)");
        __builtin_amdgcn_sched_barrier(0);
        __builtin_amdgcn_s_setprio(1);
#pragma unroll
        for (int i = 0; i < 4; ++i)
#pragma unroll
            for (int j = 2; j < 4; ++j)
#pragma unroll
                for (int s = 0; s < 2; ++s)
                    acc[i][j] = __builtin_amdgcn_mfma_f32_16x16x32_bf16(
                        a[i][s], b[j][s], acc[i][j], 0, 0, 0);
        __builtin_amdgcn_s_setprio(0);
        __builtin_amdgcn_sched_barrier(0);
        __builtin_amdgcn_s_barrier();              // all waves' B-reads complete here
        __builtin_amdgcn_sched_barrier(0);

        // ===== phase 3: stage B halves of tile t+2; Q(1,1); counted vmcnt at tile end
        if (t + 2 < T) {
#pragma unroll
            for (int h = 0; h < 2; ++h)
#pragma unroll
                for (int g = 0; g < 2; ++g)
                    gl2lds16(sB[h][g] + kb, smem + ((t & 1) << 16) + dB[h][g]);
        }
        __builtin_amdgcn_sched_barrier(0);
        __builtin_amdgcn_s_setprio(1);
#pragma unroll
        for (int i = 4; i < 8; ++i)
#pragma unroll
            for (int j = 2; j < 4; ++j)
#pragma unroll
                for (int s = 0; s < 2; ++s)
                    acc[i][j] = __builtin_amdgcn_mfma_f32_16x16x32_bf16(
                        a[i][s], b[j][s], acc[i][j], 0, 0, 0);
        __builtin_amdgcn_s_setprio(0);
        __builtin_amdgcn_sched_barrier(0);
        if (t + 2 < T) {
            // drains tile t+1 fully (+ oldest HT of t+2); leaves 3 HTs (6 loads) in flight
            asm volatile("s_waitcnt vmcnt(6)");
        } else if (t + 2 == T) {
            asm volatile("s_waitcnt vmcnt(0)");    // last prefetched tile fully resident
        }
        __builtin_amdgcn_sched_barrier(0);
        __builtin_amdgcn_s_barrier();
        __builtin_amdgcn_sched_barrier(0);
    }

    // ---- epilogue: C/D layout col = lane&15, row = (lane>>4)*4 + reg
#pragma unroll
    for (int i = 0; i < 8; ++i) {
#pragma unroll
        for (int r = 0; r < 4; ++r) {
            const size_t gr = row0 + wm * 128 + i * 16 + fq * 4 + r;
#pragma unroll
            for (int j = 0; j < 4; ++j) {
                const size_t gc  = col0 + wn * 64 + j * 16 + fr;
                const size_t idx = gr * (size_t)N + gc;
                const float v = acc[i][j][r];
                if (EPI == EPI_BIAS) {
                    ((float*)outp)[idx] = v + bias[gc];
                } else if (EPI == EPI_CMB) {
                    ((u16*)outp)[idx] = f2b(v - bias[gc]);
                } else if (EPI == EPI_W) {
                    ((u16*)outp)[idx] = f2b(v);
                } else {
                    ((float*)outp)[idx] = b2f(H[idx]) + 0.2f * (b2f(Cc[idx]) - v);
                }
            }
        }
    }
}

// ---------------------------------------------------------------- host
extern "C" void kernel_launch(void* const* d_in, const int* in_sizes, int n_in,
                              void* d_out, int out_size, void* d_ws, size_t ws_size,
                              hipStream_t stream) {
    const int B = 8192;
    const float* x      = (const float*)d_in[0];
    const float* gen_w0 = (const float*)d_in[1];
    const float* gen_b0 = (const float*)d_in[2];
    const float* rec_w0 = (const float*)d_in[3];
    const float* rec_b0 = (const float*)d_in[4];
    const float* log_p0 = (const float*)d_in[5];
    const float* ln_g0  = (const float*)d_in[6];
    const float* ln_b0  = (const float*)d_in[7];
    const float* gen_w1 = (const float*)d_in[8];
    const float* gen_b1 = (const float*)d_in[9];
    const float* rec_w1 = (const float*)d_in[10];
    const float* rec_b1 = (const float*)d_in[11];
    const float* log_p1 = (const float*)d_in[12];
    const float* ln_g1  = (const float*)d_in[13];
    const float* ln_b1  = (const float*)d_in[14];

    char* ws = (char*)d_ws;
    auto alloc = [&](size_t bytes) -> char* {
        char* p = ws;
        ws += (bytes + 255) & ~(size_t)255;
        return p;
    };
    u16*   Xb   = (u16*)  alloc((size_t)B * 4096 * 2);   // x bf16; L1-prep region after c0
    float* Tf   = (float*)alloc((size_t)B * 2048 * 4);   // pre-LN fp32
    u16*   Hb0  = (u16*)  alloc((size_t)B * 2048 * 2);
    u16*   Cb0  = (u16*)  alloc((size_t)B * 2048 * 2);   // c0 bf16; Gt0 during pre-pass
    u16*   rwb0 = (u16*)  alloc((size_t)2048 * 4096 * 2);
    u16*   DGt0 = (u16*)  alloc((size_t)2048 * 4096 * 2);// Hb1 after c0
    u16*   W0   = (u16*)  alloc((size_t)2048 * 2048 * 2);
    float* p20  = (float*)alloc(4096 * 4);
    float* p21  = (float*)alloc(2048 * 4);
    float* cv0  = (float*)alloc(2048 * 4);
    float* cv1  = (float*)alloc(1024 * 4);

    u16* Gt0 = Cb0;                       // [2048,4096] fits in Cb0
    u16* Hb1 = DGt0;                      // [8192,1024] == DGt0 size
    char* l1 = (char*)Xb;
    u16* rwb1 = (u16*)l1;                 l1 += (size_t)1024 * 2048 * 2;
    u16* Gt1  = (u16*)l1;                 l1 += (size_t)1024 * 2048 * 2;
    u16* DGt1 = (u16*)l1;                 l1 += (size_t)1024 * 2048 * 2;
    u16* W1   = (u16*)l1;                 l1 += (size_t)1024 * 1024 * 2;
    u16* Cb1  = (u16*)l1;                 l1 += (size_t)B * 1024 * 2;

    auto cast = [&](const float* s, u16* d, size_t n) {
        int n4 = (int)(n >> 2);
        cast_bf16_kernel<<<dim3((n4 + 255) / 256), dim3(256), 0, stream>>>(
            (const float4*)s, (ushort4*)d, n4);
    };
    const dim3 blk(256);
    const dim3 blk8(512);
    const size_t LDS8 = 131072;

    // ---- pre-pass (layer 0)
    prec2_kernel<<<dim3(16), blk, 0, stream>>>(log_p0, p20, 4096);
    prec2_kernel<<<dim3(8),  blk, 0, stream>>>(log_p1, p21, 2048);
    cast(x, Xb, (size_t)B * 4096);
    cast(rec_w0, rwb0, (size_t)2048 * 4096);
    transpose_cast_kernel<<<dim3(2048 / 32, 4096 / 32), blk, 0, stream>>>(
        gen_w0, Gt0, 4096, 2048, nullptr);           // Gt0[j][i] = G0[i][j]
    transpose_cast_kernel<<<dim3(2048 / 32, 4096 / 32), blk, 0, stream>>>(
        gen_w0, DGt0, 4096, 2048, p20);              // DGt0[j][i] = p2[i]*G0[i][j]
    cvec_kernel<<<dim3(2048 / 4), blk, 0, stream>>>(gen_b0, DGt0, cv0, 4096);
    // W0 = G0^T D G0  [2048,2048] bf16 (symmetric) — keep 128^2 kernel (occupancy)
    gemm_bt<EPI_W><<<dim3(16, 16), blk, 0, stream>>>(
        Gt0, DGt0, 2048, 4096, nullptr, nullptr, nullptr, W0);

    // ---- layer 0 (in=4096, hid=2048)
    gemm256<EPI_BIAS><<<dim3(8, 32), blk8, LDS8, stream>>>(
        Xb, rwb0, 2048, 4096, rec_b0, nullptr, nullptr, Tf);
    ln_kernel<0><<<dim3(B), blk, 0, stream>>>(Tf, ln_g0, ln_b0, Hb0, 2048);
    // c0 = x @ (D G0) - cv0   (last use of Xb, Gt0/Cb0 free after this writes)
    gemm256<EPI_CMB><<<dim3(8, 32), blk8, LDS8, stream>>>(
        Xb, DGt0, 2048, 4096, cv0, nullptr, nullptr, Cb0);

    // ---- L1 prep (overwrites Xb region; DGt0 still live until here — done)
    cast(rec_w1, rwb1, (size_t)1024 * 2048);
    transpose_cast_kernel<<<dim3(1024 / 32, 2048 / 32), blk, 0, stream>>>(
        gen_w1, Gt1, 2048, 1024, nullptr);
    transpose_cast_kernel<<<dim3(1024 / 32, 2048 / 32), blk, 0, stream>>>(
        gen_w1, DGt1, 2048, 1024, p21);
    cvec_kernel<<<dim3(1024 / 4), blk, 0, stream>>>(gen_b1, DGt1, cv1, 2048);
    gemm_bt<EPI_W><<<dim3(8, 8), blk, 0, stream>>>(
        Gt1, DGt1, 1024, 2048, nullptr, nullptr, nullptr, W1);

    // ---- layer 0 iterations: T = h + 0.2*(c0 - h@W0); h = LN(T)
    for (int it = 0; it < 3; ++it) {
        gemm256<EPI_ITER><<<dim3(8, 32), blk8, LDS8, stream>>>(
            Hb0, W0, 2048, 2048, nullptr, Cb0, Hb0, Tf);
        ln_kernel<0><<<dim3(B), blk, 0, stream>>>(Tf, ln_g0, ln_b0, Hb0, 2048);
    }

    // ---- layer 1 (in=2048, hid=1024); input = Hb0 (bf16)
    gemm256<EPI_BIAS><<<dim3(4, 32), blk8, LDS8, stream>>>(
        Hb0, rwb1, 1024, 2048, rec_b1, nullptr, nullptr, Tf);
    ln_kernel<0><<<dim3(B), blk, 0, stream>>>(Tf, ln_g1, ln_b1, Hb1, 1024);
    gemm256<EPI_CMB><<<dim3(4, 32), blk8, LDS8, stream>>>(
        Hb0, DGt1, 1024, 2048, cv1, nullptr, nullptr, Cb1);
    for (int it = 0; it < 3; ++it) {
        gemm256<EPI_ITER><<<dim3(4, 32), blk8, LDS8, stream>>>(
            Hb1, W1, 1024, 1024, nullptr, Cb1, Hb1, Tf);
        if (it < 2)
            ln_kernel<0><<<dim3(B), blk, 0, stream>>>(Tf, ln_g1, ln_b1, Hb1, 1024);
        else
            ln_kernel<1><<<dim3(B), blk, 0, stream>>>(Tf, ln_g1, ln_b1, d_out, 1024);
    }
}

// Round 4
// 1319.448 us; speedup vs baseline: 1.1201x; 1.1115x over previous
//
#include <hip/hip_runtime.h>

typedef unsigned short u16;
using bf16x8 = __attribute__((ext_vector_type(8))) __bf16;
using f32x4  = __attribute__((ext_vector_type(4))) float;

__device__ __forceinline__ u16 f2b(float f) {
    unsigned u = __float_as_uint(f);
    u += 0x7fffu + ((u >> 16) & 1u);   // round-to-nearest-even
    return (u16)(u >> 16);
}
__device__ __forceinline__ float b2f(u16 h) {
    return __uint_as_float(((unsigned)h) << 16);
}

// async global->LDS, 16B per lane; LDS dest = wave-uniform base + lane*16
__device__ __forceinline__ void gl2lds16(const void* g, void* l) {
    __builtin_amdgcn_global_load_lds(
        (const __attribute__((address_space(1))) void*)g,
        (__attribute__((address_space(3))) void*)l, 16, 0, 0);
}

// ---------------------------------------------------------------- elementwise
__global__ __launch_bounds__(256) void cast_bf16_kernel(
        const float4* __restrict__ src, ushort4* __restrict__ dst, int n4) {
    int i = blockIdx.x * 256 + threadIdx.x;
    if (i < n4) {
        float4 v = src[i];
        ushort4 o; o.x = f2b(v.x); o.y = f2b(v.y); o.z = f2b(v.z); o.w = f2b(v.w);
        dst[i] = o;
    }
}

__global__ __launch_bounds__(256) void prec2_kernel(
        const float* __restrict__ lp, float* __restrict__ p2, int n) {
    int i = blockIdx.x * 256 + threadIdx.x;
    if (i < n) {
        float v = lp[i];
        float sp = fmaxf(v, 0.f) + log1pf(expf(-fabsf(v)));   // stable softplus
        p2[i] = sp * sp;
    }
}

// src[R][C] f32 -> dst[C][R] bf16, optionally scaled by scale[src_row]
__global__ __launch_bounds__(256) void transpose_cast_kernel(
        const float* __restrict__ src, u16* __restrict__ dst, int R, int C,
        const float* __restrict__ scale) {
    __shared__ float tile[32][33];
    const int bx = blockIdx.x * 32;      // col block in src
    const int by = blockIdx.y * 32;      // row block in src
    const int tx = threadIdx.x & 31;
    const int ty = threadIdx.x >> 5;     // 0..7
#pragma unroll
    for (int i = 0; i < 32; i += 8) {
        float s = scale ? scale[by + ty + i] : 1.f;
        tile[ty + i][tx] = s * src[(size_t)(by + ty + i) * C + (bx + tx)];
    }
    __syncthreads();
#pragma unroll
    for (int i = 0; i < 32; i += 8)
        dst[(size_t)(bx + ty + i) * R + (by + tx)] = f2b(tile[tx][ty + i]);
}

// cvec[j] = sum_i gb[i] * DGt[j][i]; one wave per j
__global__ __launch_bounds__(256) void cvec_kernel(
        const float* __restrict__ gb, const u16* __restrict__ DGt,
        float* __restrict__ cv, int in) {
    const int j = blockIdx.x * 4 + (threadIdx.x >> 6);
    const int lane = threadIdx.x & 63;
    const u16* row = DGt + (size_t)j * in;
    float s = 0.f;
    for (int i = lane; i < in; i += 64) s += gb[i] * b2f(row[i]);
#pragma unroll
    for (int off = 32; off > 0; off >>= 1) s += __shfl_down(s, off);
    if (lane == 0) cv[j] = s;
}

// ---------------------------------------------------------------- layernorm
template <int F32OUT>
__global__ __launch_bounds__(256) void ln_kernel(
        const float* __restrict__ T, const float* __restrict__ g,
        const float* __restrict__ b, void* __restrict__ outp, int D) {
    const int row = blockIdx.x;
    const int tid = threadIdx.x;
    const int nv  = D >> 2;
    const float4* rp = (const float4*)(T + (size_t)row * D);

    float4 vals[2];
    float s = 0.f, sq = 0.f;
    int cnt = 0;
    for (int i = tid; i < nv; i += 256) {
        float4 v = rp[i];
        vals[cnt++] = v;
        s  += v.x + v.y + v.z + v.w;
        sq += v.x * v.x + v.y * v.y + v.z * v.z + v.w * v.w;
    }
#pragma unroll
    for (int off = 32; off > 0; off >>= 1) {
        s  += __shfl_down(s, off);
        sq += __shfl_down(sq, off);
    }
    __shared__ float ssum[4], ssq[4];
    if ((tid & 63) == 0) { ssum[tid >> 6] = s; ssq[tid >> 6] = sq; }
    __syncthreads();
    const float ts = ssum[0] + ssum[1] + ssum[2] + ssum[3];
    const float tq = ssq[0] + ssq[1] + ssq[2] + ssq[3];
    const float mu   = ts / (float)D;
    const float rstd = rsqrtf(tq / (float)D - mu * mu + 1e-5f);

    cnt = 0;
    for (int i = tid; i < nv; i += 256) {
        float4 v  = vals[cnt++];
        float4 gg = ((const float4*)g)[i];
        float4 bb = ((const float4*)b)[i];
        float o0 = (v.x - mu) * rstd * gg.x + bb.x;
        float o1 = (v.y - mu) * rstd * gg.y + bb.y;
        float o2 = (v.z - mu) * rstd * gg.z + bb.z;
        float o3 = (v.w - mu) * rstd * gg.w + bb.w;
        if (F32OUT) {
            ((float4*)outp)[(size_t)row * nv + i] = make_float4(o0, o1, o2, o3);
        } else {
            ushort4 o; o.x = f2b(o0); o.y = f2b(o1); o.z = f2b(o2); o.w = f2b(o3);
            ((ushort4*)outp)[(size_t)row * nv + i] = o;
        }
    }
}

// ---------------------------------------------------------------- GEMM epilogues
enum { EPI_BIAS = 0, EPI_CMB = 1, EPI_W = 2, EPI_ITER = 3 };

// ---------------------------------------------------------------- GEMM 128x128 (m97 structure)
// used for W = G^T D G and for all N=1024 layer-1 GEMMs (512-block grid -> full GPU,
// ~3 blocks/CU inter-block overlap; the 256^2 kernel would only fill half the CUs there)
template <int EPI>
__global__ __launch_bounds__(256) void gemm_bt(
        const u16* __restrict__ A, const u16* __restrict__ Bt, int N, int K,
        const float* __restrict__ bias, const u16* __restrict__ Cc,
        const u16* __restrict__ H, void* __restrict__ outp) {
    __shared__ u16 As[128 * 32];
    __shared__ u16 Bs[128 * 32];

    const int tid  = threadIdx.x;
    const int lane = tid & 63;
    const int wave = tid >> 6;
    const size_t row0 = (size_t)blockIdx.y * 128;
    const size_t col0 = (size_t)blockIdx.x * 128;

    const int sr = tid >> 2;
    const int sc = (tid & 3) * 8;
    const u16* gA0 = A  + (row0 + sr) * K + sc;
    const u16* gA1 = gA0 + (size_t)64 * K;
    const u16* gB0 = Bt + (col0 + sr) * K + sc;
    const u16* gB1 = gB0 + (size_t)64 * K;
    char* lA = (char*)As + wave * 1024;
    char* lB = (char*)Bs + wave * 1024;

    const int wm = wave >> 1, wn = wave & 1;
    const int fr = lane & 15;
    const int fq = lane >> 4;
    const bf16x8* aP[4];
    const bf16x8* bP[4];
#pragma unroll
    for (int i = 0; i < 4; ++i) {
        aP[i] = (const bf16x8*)(As + (wm * 64 + i * 16 + fr) * 32 + fq * 8);
        bP[i] = (const bf16x8*)(Bs + (wn * 64 + i * 16 + fr) * 32 + fq * 8);
    }

    f32x4 acc[4][4];
    const f32x4 zero = {0.f, 0.f, 0.f, 0.f};
#pragma unroll
    for (int i = 0; i < 4; ++i)
#pragma unroll
        for (int j = 0; j < 4; ++j) acc[i][j] = zero;

    for (int k0 = 0; k0 < K; k0 += 32) {
        __syncthreads();
        gl2lds16(gA0, lA);
        gl2lds16(gA1, lA + 4096);
        gl2lds16(gB0, lB);
        gl2lds16(gB1, lB + 4096);
        __syncthreads();
        bf16x8 af[4], bfr[4];
#pragma unroll
        for (int i = 0; i < 4; ++i) { af[i] = *aP[i]; bfr[i] = *bP[i]; }
#pragma unroll
        for (int i = 0; i < 4; ++i)
#pragma unroll
            for (int j = 0; j < 4; ++j)
                acc[i][j] = __builtin_amdgcn_mfma_f32_16x16x32_bf16(
                    af[i], bfr[j], acc[i][j], 0, 0, 0);
        gA0 += 32; gA1 += 32; gB0 += 32; gB1 += 32;
    }

#pragma unroll
    for (int i = 0; i < 4; ++i) {
#pragma unroll
        for (int r = 0; r < 4; ++r) {
            const size_t gr = row0 + wm * 64 + i * 16 + fq * 4 + r;
#pragma unroll
            for (int j = 0; j < 4; ++j) {
                const size_t gc  = col0 + wn * 64 + j * 16 + fr;
                const size_t idx = gr * (size_t)N + gc;
                const float v = acc[i][j][r];
                if (EPI == EPI_BIAS) {
                    ((float*)outp)[idx] = v + bias[gc];
                } else if (EPI == EPI_CMB) {
                    ((u16*)outp)[idx] = f2b(v - bias[gc]);
                } else if (EPI == EPI_W) {
                    ((u16*)outp)[idx] = f2b(v);
                } else {
                    ((float*)outp)[idx] = b2f(H[idx]) + 0.2f * (b2f(Cc[idx]) - v);
                }
            }
        }
    }
}

// ---------------------------------------------------------------- GEMM 256x256
// C[M,N] = A[M,K] (bf16 rm) x Bt[N,K]^T.  512 thr = 8 waves (2Mx4N), BK=64,
// 128 KiB LDS double-buffered, 16B-granular XOR swizzle (both sides, rule #21).
// De-lockstepped schedule: only TWO s_barriers per K-tile (the staging guards).
// No sched_barrier fences, no asm lgkmcnt — data waits are compiler-inserted
// (precise per-consumer), so ds_read issue overlaps MFMA clusters and waves slip.
// vmcnt discipline (counted, never 0 mid-loop):
//   VM queue invariant entering tile t: [A(t+1) x4, B(t+1) x4]
//   BAR#1 (end ph1): vmcnt(4) -> A(t+1) resident (all waves after barrier)
//   BAR#2 (end ph2): stage A(t+2) issued; vmcnt(4) -> B(t+1) resident
//                    (vmcnt(0) on the t+2>=T edge, where no staging was issued)
// Staging-overwrite guards: A-stage(t+2) after BAR#1 (all waves' a03/a47 reads of
// buf done); B-stage(t+2) after BAR#2 (all waves' b01/b23 reads done).
// Requires: M%256==0, N%256==0, K%64==0, K>=128.
template <int EPI>
__global__ __launch_bounds__(512, 2) void gemm256(
        const u16* __restrict__ A, const u16* __restrict__ Bt, int N, int K,
        const float* __restrict__ bias, const u16* __restrict__ Cc,
        const u16* __restrict__ H, void* __restrict__ outp) {
    extern __shared__ char smem[];   // 131072 B: buf b at b*65536; A halves +0,+16K; B halves +32K,+48K

    const int tid  = threadIdx.x;
    const int lane = tid & 63;
    const int w    = tid >> 6;       // 0..7
    const int wm   = w >> 2;         // 0..1
    const int wn   = w & 3;          // 0..3
    const int fr   = lane & 15;
    const int fq   = lane >> 4;      // 0..3

    // bijective XCD-aware block swizzle (all launches have nwg % 8 == 0)
    const int nwg = gridDim.x * gridDim.y;
    const int bid = blockIdx.y * gridDim.x + blockIdx.x;
    int sbid = bid;
    if (!(nwg & 7)) sbid = (bid & 7) * (nwg >> 3) + (bid >> 3);
    const int bx = sbid % gridDim.x;
    const int by = sbid / gridDim.x;
    const size_t row0 = (size_t)by * 256;
    const size_t col0 = (size_t)bx * 256;

    // ---- staging: pre-swizzled global source so linear LDS writes land swizzled.
    // lane l covers row (base + l>>3), phys bytes (l&7)*16; logical col16 = (l&7)^(l>>3).
    const int scol = ((lane & 7) ^ (lane >> 3)) << 4;
    const char* sA[2][2];
    const char* sB[2][2];
    int dA[2][2], dB[2][2];
#pragma unroll
    for (int h = 0; h < 2; ++h)
#pragma unroll
        for (int g = 0; g < 2; ++g) {
            const size_t rr = (size_t)(h * 128 + g * 64 + w * 8 + (lane >> 3));
            sA[h][g] = (const char*)A  + (row0 + rr) * (size_t)K * 2 + scol;
            sB[h][g] = (const char*)Bt + (col0 + rr) * (size_t)K * 2 + scol;
            dA[h][g] = h * 16384 + (g * 64 + w * 8) * 128;
            dB[h][g] = 32768 + dA[h][g];
        }

    // ---- fragment read offsets: logical byte (within half) = r*128 + s*64 + fq*16,
    // phys = logical ^ ((r&7)<<4); r&7 == fr&7 for both A and B row patterns.
    const int swzR = (fr & 7) << 4;
    int aoff[2], boff[2];
#pragma unroll
    for (int s = 0; s < 2; ++s) {
        aoff[s] = ((fr * 128 + s * 64 + fq * 16) ^ swzR) + wm * 16384;
        boff[s] = ((((wn & 1) * 64 + fr) * 128 + s * 64 + fq * 16) ^ swzR)
                  + 32768 + (wn >> 1) * 16384;
    }

    f32x4 acc[8][4];
    const f32x4 zero = {0.f, 0.f, 0.f, 0.f};
#pragma unroll
    for (int i = 0; i < 8; ++i)
#pragma unroll
        for (int j = 0; j < 4; ++j) acc[i][j] = zero;

    // ---- prologue: stage K-tile 0 -> buf0 (8 issues), K-tile 1 -> buf1 (8 issues)
#pragma unroll
    for (int h = 0; h < 2; ++h)
#pragma unroll
        for (int g = 0; g < 2; ++g) {
            gl2lds16(sA[h][g], smem + dA[h][g]);
            gl2lds16(sB[h][g], smem + dB[h][g]);
        }
#pragma unroll
    for (int h = 0; h < 2; ++h)
#pragma unroll
        for (int g = 0; g < 2; ++g) {
            gl2lds16(sA[h][g] + 128, smem + 65536 + dA[h][g]);
            gl2lds16(sB[h][g] + 128, smem + 65536 + dB[h][g]);
        }
    asm volatile("s_waitcnt vmcnt(8)" ::: "memory");   // tile 0 resident; tile 1 in flight
    __builtin_amdgcn_s_barrier();

    const int T = K >> 6;
    for (int t = 0; t < T; ++t) {
        const char* base = smem + ((t & 1) << 16);
        const int kb = (t + 2) * 128;              // byte offset of tile t+2 in global rows
        bf16x8 a[8][2], b[4][2];

        // ===== ph0: read a03,b01; MFMA Q(0,0)  (region shared with prev ph3 + ph1)
#pragma unroll
        for (int i = 0; i < 4; ++i)
#pragma unroll
            for (int s = 0; s < 2; ++s)
                a[i][s] = *(const bf16x8*)(base + aoff[s] + i * 2048);
#pragma unroll
        for (int j = 0; j < 2; ++j)
#pragma unroll
            for (int s = 0; s < 2; ++s)
                b[j][s] = *(const bf16x8*)(base + boff[s] + j * 2048);
        __builtin_amdgcn_s_setprio(1);
#pragma unroll
        for (int i = 0; i < 4; ++i)
#pragma unroll
            for (int j = 0; j < 2; ++j)
#pragma unroll
                for (int s = 0; s < 2; ++s)
                    acc[i][j] = __builtin_amdgcn_mfma_f32_16x16x32_bf16(
                        a[i][s], b[j][s], acc[i][j], 0, 0, 0);
        __builtin_amdgcn_s_setprio(0);

        // ===== ph1: read a47; MFMA Q(1,0); vmcnt(4); BAR#1
#pragma unroll
        for (int i = 4; i < 8; ++i)
#pragma unroll
            for (int s = 0; s < 2; ++s)
                a[i][s] = *(const bf16x8*)(base + aoff[s] + i * 2048);
        __builtin_amdgcn_s_setprio(1);
#pragma unroll
        for (int i = 4; i < 8; ++i)
#pragma unroll
            for (int j = 0; j < 2; ++j)
#pragma unroll
                for (int s = 0; s < 2; ++s)
                    acc[i][j] = __builtin_amdgcn_mfma_f32_16x16x32_bf16(
                        a[i][s], b[j][s], acc[i][j], 0, 0, 0);
        __builtin_amdgcn_s_setprio(0);
        asm volatile("s_waitcnt vmcnt(4)" ::: "memory");   // A(t+1) resident
        __builtin_amdgcn_s_barrier();                      // BAR#1: A reads done, all waves

        // ===== ph2: stage A(t+2); read b23; MFMA Q(0,1); vmcnt; BAR#2
        if (t + 2 < T) {
#pragma unroll
            for (int h = 0; h < 2; ++h)
#pragma unroll
                for (int g = 0; g < 2; ++g)
                    gl2lds16(sA[h][g] + kb, smem + ((t & 1) << 16) + dA[h][g]);
        }
#pragma unroll
        for (int j = 2; j < 4; ++j)
#pragma unroll
            for (int s = 0; s < 2; ++s)
                b[j][s] = *(const bf16x8*)(base + boff[s] + j * 2048);
        __builtin_amdgcn_s_setprio(1);
#pragma unroll
        for (int i = 0; i < 4; ++i)
#pragma unroll
            for (int j = 2; j < 4; ++j)
#pragma unroll
                for (int s = 0; s < 2; ++s)
                    acc[i][j] = __builtin_amdgcn_mfma_f32_16x16x32_bf16(
                        a[i][s], b[j][s], acc[i][j], 0, 0, 0);
        __builtin_amdgcn_s_setprio(0);
        if (t + 2 < T) {
            asm volatile("s_waitcnt vmcnt(4)" ::: "memory");  // B(t+1) resident
        } else {
            asm volatile("s_waitcnt vmcnt(0)" ::: "memory");  // tail: no staging queued
        }
        __builtin_amdgcn_s_barrier();                      // BAR#2: B reads done, all waves

        // ===== ph3: stage B(t+2); MFMA Q(1,1)  (no barrier; flows into next ph0)
        if (t + 2 < T) {
#pragma unroll
            for (int h = 0; h < 2; ++h)
#pragma unroll
                for (int g = 0; g < 2; ++g)
                    gl2lds16(sB[h][g] + kb, smem + ((t & 1) << 16) + dB[h][g]);
        }
        __builtin_amdgcn_s_setprio(1);
#pragma unroll
        for (int i = 4; i < 8; ++i)
#pragma unroll
            for (int j = 2; j < 4; ++j)
#pragma unroll
                for (int s = 0; s < 2; ++s)
                    acc[i][j] = __builtin_amdgcn_mfma_f32_16x16x32_bf16(
                        a[i][s], b[j][s], acc[i][j], 0, 0, 0);
        __builtin_amdgcn_s_setprio(0);
    }

    // ---- epilogue: C/D layout col = lane&15, row = (lane>>4)*4 + reg
#pragma unroll
    for (int i = 0; i < 8; ++i) {
#pragma unroll
        for (int r = 0; r < 4; ++r) {
            const size_t gr = row0 + wm * 128 + i * 16 + fq * 4 + r;
#pragma unroll
            for (int j = 0; j < 4; ++j) {
                const size_t gc  = col0 + wn * 64 + j * 16 + fr;
                const size_t idx = gr * (size_t)N + gc;
                const float v = acc[i][j][r];
                if (EPI == EPI_BIAS) {
                    ((float*)outp)[idx] = v + bias[gc];
                } else if (EPI == EPI_CMB) {
                    ((u16*)outp)[idx] = f2b(v - bias[gc]);
                } else if (EPI == EPI_W) {
                    ((u16*)outp)[idx] = f2b(v);
                } else {
                    ((float*)outp)[idx] = b2f(H[idx]) + 0.2f * (b2f(Cc[idx]) - v);
                }
            }
        }
    }
}

// ---------------------------------------------------------------- host
extern "C" void kernel_launch(void* const* d_in, const int* in_sizes, int n_in,
                              void* d_out, int out_size, void* d_ws, size_t ws_size,
                              hipStream_t stream) {
    const int B = 8192;
    const float* x      = (const float*)d_in[0];
    const float* gen_w0 = (const float*)d_in[1];
    const float* gen_b0 = (const float*)d_in[2];
    const float* rec_w0 = (const float*)d_in[3];
    const float* rec_b0 = (const float*)d_in[4];
    const float* log_p0 = (const float*)d_in[5];
    const float* ln_g0  = (const float*)d_in[6];
    const float* ln_b0  = (const float*)d_in[7];
    const float* gen_w1 = (const float*)d_in[8];
    const float* gen_b1 = (const float*)d_in[9];
    const float* rec_w1 = (const float*)d_in[10];
    const float* rec_b1 = (const float*)d_in[11];
    const float* log_p1 = (const float*)d_in[12];
    const float* ln_g1  = (const float*)d_in[13];
    const float* ln_b1  = (const float*)d_in[14];

    char* ws = (char*)d_ws;
    auto alloc = [&](size_t bytes) -> char* {
        char* p = ws;
        ws += (bytes + 255) & ~(size_t)255;
        return p;
    };
    u16*   Xb   = (u16*)  alloc((size_t)B * 4096 * 2);   // x bf16; L1-prep region after c0
    float* Tf   = (float*)alloc((size_t)B * 2048 * 4);   // pre-LN fp32
    u16*   Hb0  = (u16*)  alloc((size_t)B * 2048 * 2);
    u16*   Cb0  = (u16*)  alloc((size_t)B * 2048 * 2);   // c0 bf16; Gt0 during pre-pass
    u16*   rwb0 = (u16*)  alloc((size_t)2048 * 4096 * 2);
    u16*   DGt0 = (u16*)  alloc((size_t)2048 * 4096 * 2);// Hb1 after c0
    u16*   W0   = (u16*)  alloc((size_t)2048 * 2048 * 2);
    float* p20  = (float*)alloc(4096 * 4);
    float* p21  = (float*)alloc(2048 * 4);
    float* cv0  = (float*)alloc(2048 * 4);
    float* cv1  = (float*)alloc(1024 * 4);

    u16* Gt0 = Cb0;                       // [2048,4096] fits in Cb0
    u16* Hb1 = DGt0;                      // [8192,1024] == DGt0 size
    char* l1 = (char*)Xb;
    u16* rwb1 = (u16*)l1;                 l1 += (size_t)1024 * 2048 * 2;
    u16* Gt1  = (u16*)l1;                 l1 += (size_t)1024 * 2048 * 2;
    u16* DGt1 = (u16*)l1;                 l1 += (size_t)1024 * 2048 * 2;
    u16* W1   = (u16*)l1;                 l1 += (size_t)1024 * 1024 * 2;
    u16* Cb1  = (u16*)l1;                 l1 += (size_t)B * 1024 * 2;

    auto cast = [&](const float* s, u16* d, size_t n) {
        int n4 = (int)(n >> 2);
        cast_bf16_kernel<<<dim3((n4 + 255) / 256), dim3(256), 0, stream>>>(
            (const float4*)s, (ushort4*)d, n4);
    };
    const dim3 blk(256);
    const dim3 blk8(512);
    const size_t LDS8 = 131072;

    // ---- pre-pass (layer 0)
    prec2_kernel<<<dim3(16), blk, 0, stream>>>(log_p0, p20, 4096);
    prec2_kernel<<<dim3(8),  blk, 0, stream>>>(log_p1, p21, 2048);
    cast(x, Xb, (size_t)B * 4096);
    cast(rec_w0, rwb0, (size_t)2048 * 4096);
    transpose_cast_kernel<<<dim3(2048 / 32, 4096 / 32), blk, 0, stream>>>(
        gen_w0, Gt0, 4096, 2048, nullptr);           // Gt0[j][i] = G0[i][j]
    transpose_cast_kernel<<<dim3(2048 / 32, 4096 / 32), blk, 0, stream>>>(
        gen_w0, DGt0, 4096, 2048, p20);              // DGt0[j][i] = p2[i]*G0[i][j]
    cvec_kernel<<<dim3(2048 / 4), blk, 0, stream>>>(gen_b0, DGt0, cv0, 4096);
    // W0 = G0^T D G0  [2048,2048] bf16 (symmetric)
    gemm_bt<EPI_W><<<dim3(16, 16), blk, 0, stream>>>(
        Gt0, DGt0, 2048, 4096, nullptr, nullptr, nullptr, W0);

    // ---- layer 0 (in=4096, hid=2048)
    gemm256<EPI_BIAS><<<dim3(8, 32), blk8, LDS8, stream>>>(
        Xb, rwb0, 2048, 4096, rec_b0, nullptr, nullptr, Tf);
    ln_kernel<0><<<dim3(B), blk, 0, stream>>>(Tf, ln_g0, ln_b0, Hb0, 2048);
    // c0 = x @ (D G0) - cv0   (last use of Xb, Gt0/Cb0 free after this writes)
    gemm256<EPI_CMB><<<dim3(8, 32), blk8, LDS8, stream>>>(
        Xb, DGt0, 2048, 4096, cv0, nullptr, nullptr, Cb0);

    // ---- L1 prep (overwrites Xb region; DGt0 still live until here — done)
    cast(rec_w1, rwb1, (size_t)1024 * 2048);
    transpose_cast_kernel<<<dim3(1024 / 32, 2048 / 32), blk, 0, stream>>>(
        gen_w1, Gt1, 2048, 1024, nullptr);
    transpose_cast_kernel<<<dim3(1024 / 32, 2048 / 32), blk, 0, stream>>>(
        gen_w1, DGt1, 2048, 1024, p21);
    cvec_kernel<<<dim3(1024 / 4), blk, 0, stream>>>(gen_b1, DGt1, cv1, 2048);
    gemm_bt<EPI_W><<<dim3(8, 8), blk, 0, stream>>>(
        Gt1, DGt1, 1024, 2048, nullptr, nullptr, nullptr, W1);

    // ---- layer 0 iterations: T = h + 0.2*(c0 - h@W0); h = LN(T)
    for (int it = 0; it < 3; ++it) {
        gemm256<EPI_ITER><<<dim3(8, 32), blk8, LDS8, stream>>>(
            Hb0, W0, 2048, 2048, nullptr, Cb0, Hb0, Tf);
        ln_kernel<0><<<dim3(B), blk, 0, stream>>>(Tf, ln_g0, ln_b0, Hb0, 2048);
    }

    // ---- layer 1 (in=2048, hid=1024); input = Hb0 (bf16)
    // N=1024 -> 128^2 kernel with 512-block grid (gemm256 would only fill 128 CUs)
    gemm_bt<EPI_BIAS><<<dim3(8, 64), blk, 0, stream>>>(
        Hb0, rwb1, 1024, 2048, rec_b1, nullptr, nullptr, Tf);
    ln_kernel<0><<<dim3(B), blk, 0, stream>>>(Tf, ln_g1, ln_b1, Hb1, 1024);
    gemm_bt<EPI_CMB><<<dim3(8, 64), blk, 0, stream>>>(
        Hb0, DGt1, 1024, 2048, cv1, nullptr, nullptr, Cb1);
    for (int it = 0; it < 3; ++it) {
        gemm_bt<EPI_ITER><<<dim3(8, 64), blk, 0, stream>>>(
            Hb1, W1, 1024, 1024, nullptr, Cb1, Hb1, Tf);
        if (it < 2)
            ln_kernel<0><<<dim3(B), blk, 0, stream>>>(Tf, ln_g1, ln_b1, Hb1, 1024);
        else
            ln_kernel<1><<<dim3(B), blk, 0, stream>>>(Tf, ln_g1, ln_b1, d_out, 1024);
    }
}

// Round 5
// 1261.019 us; speedup vs baseline: 1.1720x; 1.0463x over previous
//
#include <hip/hip_runtime.h>

typedef unsigned short u16;
using bf16x8 = __attribute__((ext_vector_type(8))) __bf16;
using f32x4  = __attribute__((ext_vector_type(4))) float;

__device__ __forceinline__ u16 f2b(float f) {
    unsigned u = __float_as_uint(f);
    u += 0x7fffu + ((u >> 16) & 1u);   // round-to-nearest-even
    return (u16)(u >> 16);
}
__device__ __forceinline__ float b2f(u16 h) {
    return __uint_as_float(((unsigned)h) << 16);
}

// async global->LDS, 16B per lane; LDS dest = wave-uniform base + lane*16
__device__ __forceinline__ void gl2lds16(const void* g, void* l) {
    __builtin_amdgcn_global_load_lds(
        (const __attribute__((address_space(1))) void*)g,
        (__attribute__((address_space(3))) void*)l, 16, 0, 0);
}

// ---------------------------------------------------------------- elementwise
__global__ __launch_bounds__(256) void cast_bf16_kernel(
        const float4* __restrict__ src, ushort4* __restrict__ dst, int n4) {
    int i = blockIdx.x * 256 + threadIdx.x;
    if (i < n4) {
        float4 v = src[i];
        ushort4 o; o.x = f2b(v.x); o.y = f2b(v.y); o.z = f2b(v.z); o.w = f2b(v.w);
        dst[i] = o;
    }
}

__global__ __launch_bounds__(256) void prec2_kernel(
        const float* __restrict__ lp, float* __restrict__ p2, int n) {
    int i = blockIdx.x * 256 + threadIdx.x;
    if (i < n) {
        float v = lp[i];
        float sp = fmaxf(v, 0.f) + log1pf(expf(-fabsf(v)));   // stable softplus
        p2[i] = sp * sp;
    }
}

// src[R][C] f32 -> dst[C][R] bf16, optionally scaled by scale[src_row]
__global__ __launch_bounds__(256) void transpose_cast_kernel(
        const float* __restrict__ src, u16* __restrict__ dst, int R, int C,
        const float* __restrict__ scale) {
    __shared__ float tile[32][33];
    const int bx = blockIdx.x * 32;      // col block in src
    const int by = blockIdx.y * 32;      // row block in src
    const int tx = threadIdx.x & 31;
    const int ty = threadIdx.x >> 5;     // 0..7
#pragma unroll
    for (int i = 0; i < 32; i += 8) {
        float s = scale ? scale[by + ty + i] : 1.f;
        tile[ty + i][tx] = s * src[(size_t)(by + ty + i) * C + (bx + tx)];
    }
    __syncthreads();
#pragma unroll
    for (int i = 0; i < 32; i += 8)
        dst[(size_t)(bx + ty + i) * R + (by + tx)] = f2b(tile[tx][ty + i]);
}

// cvec[j] = sum_i gb[i] * DGt[j][i]; one wave per j
__global__ __launch_bounds__(256) void cvec_kernel(
        const float* __restrict__ gb, const u16* __restrict__ DGt,
        float* __restrict__ cv, int in) {
    const int j = blockIdx.x * 4 + (threadIdx.x >> 6);
    const int lane = threadIdx.x & 63;
    const u16* row = DGt + (size_t)j * in;
    float s = 0.f;
    for (int i = lane; i < in; i += 64) s += gb[i] * b2f(row[i]);
#pragma unroll
    for (int off = 32; off > 0; off >>= 1) s += __shfl_down(s, off);
    if (lane == 0) cv[j] = s;
}

// ---------------------------------------------------------------- layernorm
template <int F32OUT>
__global__ __launch_bounds__(256) void ln_kernel(
        const float* __restrict__ T, const float* __restrict__ g,
        const float* __restrict__ b, void* __restrict__ outp, int D) {
    const int row = blockIdx.x;
    const int tid = threadIdx.x;
    const int nv  = D >> 2;
    const float4* rp = (const float4*)(T + (size_t)row * D);

    float4 vals[2];
    float s = 0.f, sq = 0.f;
    int cnt = 0;
    for (int i = tid; i < nv; i += 256) {
        float4 v = rp[i];
        vals[cnt++] = v;
        s  += v.x + v.y + v.z + v.w;
        sq += v.x * v.x + v.y * v.y + v.z * v.z + v.w * v.w;
    }
#pragma unroll
    for (int off = 32; off > 0; off >>= 1) {
        s  += __shfl_down(s, off);
        sq += __shfl_down(sq, off);
    }
    __shared__ float ssum[4], ssq[4];
    if ((tid & 63) == 0) { ssum[tid >> 6] = s; ssq[tid >> 6] = sq; }
    __syncthreads();
    const float ts = ssum[0] + ssum[1] + ssum[2] + ssum[3];
    const float tq = ssq[0] + ssq[1] + ssq[2] + ssq[3];
    const float mu   = ts / (float)D;
    const float rstd = rsqrtf(tq / (float)D - mu * mu + 1e-5f);

    cnt = 0;
    for (int i = tid; i < nv; i += 256) {
        float4 v  = vals[cnt++];
        float4 gg = ((const float4*)g)[i];
        float4 bb = ((const float4*)b)[i];
        float o0 = (v.x - mu) * rstd * gg.x + bb.x;
        float o1 = (v.y - mu) * rstd * gg.y + bb.y;
        float o2 = (v.z - mu) * rstd * gg.z + bb.z;
        float o3 = (v.w - mu) * rstd * gg.w + bb.w;
        if (F32OUT) {
            ((float4*)outp)[(size_t)row * nv + i] = make_float4(o0, o1, o2, o3);
        } else {
            ushort4 o; o.x = f2b(o0); o.y = f2b(o1); o.z = f2b(o2); o.w = f2b(o3);
            ((ushort4*)outp)[(size_t)row * nv + i] = o;
        }
    }
}

// ---------------------------------------------------------------- GEMM epilogues
enum { EPI_BIAS = 0, EPI_CMB = 1, EPI_W = 2, EPI_ITER = 3 };

// ---------------------------------------------------------------- GEMM 128x128
// C[M,N] = A[M,K] (bf16 rm) x Bt[N,K]^T.  256 thr = 4 waves (2Mx2N), BK=64,
// 64 KiB LDS double-buffered -> 2 BLOCKS/CU (LDS 128<=160 KiB, ~170 regs/wave
// under the (256,2) 256-reg cap with ~90 regs scheduling headroom).
// Independent co-resident blocks de-phase: one block's barrier/vmcnt stalls are
// covered by the other's MFMA.
// LDS swizzle (16B granularity): phys = logical ^ ((row&7) << 4), both sides:
//   staging keeps linear LDS dest and pre-swizzles the GLOBAL source column
//   (col16 = (lane&7) ^ ((lane>>3)&7); issue base rows are %8==0);
//   fragment ds_read XORs (fr&7)<<4 (A rows i*16+fr, B rows j*16+fr: row&7==fr&7).
// Schedule per K-tile (2 barriers, loose; no sched_barrier, no asm lgkmcnt —
// data waits are compiler-inserted):
//   ph0: read a[0..3][s], b[0..1][s]; MFMA j=0,1;  BAR#1 (A-region read-done)
//   ph1: stage A(t+2); read b[2..3][s]; MFMA j=2,3; vmcnt(4) [A(t+1),B(t+1)
//        resident; A(t+2) left in flight; vmcnt(0) on t+2>=T edge]; BAR#2
//   ph2: stage B(t+2)   (flows into next tile's ph0)
// Queue invariant entering tile t: [A(t+1) x4, B(t+1) x4].
// Requires: M%128==0, N%128==0, K%64==0, K>=128.
template <int EPI>
__global__ __launch_bounds__(256, 2) void gemm128(
        const u16* __restrict__ A, const u16* __restrict__ Bt, int N, int K,
        const float* __restrict__ bias, const u16* __restrict__ Cc,
        const u16* __restrict__ H, void* __restrict__ outp) {
    extern __shared__ char smem[];   // 65536 B: buf p at p*32768; A +0, B +16384

    const int tid  = threadIdx.x;
    const int lane = tid & 63;
    const int w    = tid >> 6;       // 0..3
    const int wm   = w >> 1;         // 0..1
    const int wn   = w & 1;          // 0..1
    const int fr   = lane & 15;
    const int fq   = lane >> 4;      // 0..3

    // bijective XCD-aware block swizzle (all launches have nwg % 8 == 0)
    const int nwg = gridDim.x * gridDim.y;
    const int bid = blockIdx.y * gridDim.x + blockIdx.x;
    int sbid = bid;
    if (!(nwg & 7)) sbid = (bid & 7) * (nwg >> 3) + (bid >> 3);
    const int bx = sbid % gridDim.x;
    const int by = sbid / gridDim.x;
    const size_t row0 = (size_t)by * 128;
    const size_t col0 = (size_t)bx * 128;

    // ---- staging: pre-swizzled global source so linear LDS writes land swizzled.
    // issue g covers rows g*32..g*32+31; wave w: rows g*32+w*8+(lane>>3), slot lane&7.
    const int scol = (((lane & 7) ^ ((lane >> 3) & 7)) << 4);
    const char* sA[4];
    const char* sB[4];
    int dA[4], dB[4];
#pragma unroll
    for (int g = 0; g < 4; ++g) {
        const size_t rr = (size_t)(g * 32 + w * 8 + (lane >> 3));
        sA[g] = (const char*)A  + (row0 + rr) * (size_t)K * 2 + scol;
        sB[g] = (const char*)Bt + (col0 + rr) * (size_t)K * 2 + scol;
        dA[g] = g * 4096 + w * 1024;
        dB[g] = 16384 + dA[g];
    }

    // ---- fragment read offsets: logical byte (in A/B region) = R*128 + s*64 + fq*16,
    // phys slot16 = (s*4 + fq) ^ (R&7); R&7 == fr&7 for rows R = {wm,wn}*64 + i*16 + fr.
    int aoff[2], boff[2];
#pragma unroll
    for (int s = 0; s < 2; ++s) {
        const int slot = (((s << 2) | fq) ^ (fr & 7)) << 4;
        aoff[s] = (wm * 64 + fr) * 128 + slot;
        boff[s] = 16384 + (wn * 64 + fr) * 128 + slot;
    }

    f32x4 acc[4][4];
    const f32x4 zero = {0.f, 0.f, 0.f, 0.f};
#pragma unroll
    for (int i = 0; i < 4; ++i)
#pragma unroll
        for (int j = 0; j < 4; ++j) acc[i][j] = zero;

    // ---- prologue: stage K-tile 0 -> buf0 (8 issues), K-tile 1 -> buf1 (8 issues)
#pragma unroll
    for (int g = 0; g < 4; ++g) {
        gl2lds16(sA[g], smem + dA[g]);
        gl2lds16(sB[g], smem + dB[g]);
    }
#pragma unroll
    for (int g = 0; g < 4; ++g) {
        gl2lds16(sA[g] + 128, smem + 32768 + dA[g]);
        gl2lds16(sB[g] + 128, smem + 32768 + dB[g]);
    }
    asm volatile("s_waitcnt vmcnt(8)" ::: "memory");   // tile 0 resident; tile 1 in flight
    __builtin_amdgcn_s_barrier();

    const int T = K >> 6;
    for (int t = 0; t < T; ++t) {
        const char* base = smem + ((t & 1) << 15);
        const int kb = (t + 2) * 128;              // byte offset of tile t+2 in global rows
        bf16x8 a[4][2], b[4][2];

        // ===== ph0: read a[0..3], b[0..1]; MFMA j=0,1
#pragma unroll
        for (int i = 0; i < 4; ++i)
#pragma unroll
            for (int s = 0; s < 2; ++s)
                a[i][s] = *(const bf16x8*)(base + aoff[s] + i * 2048);
#pragma unroll
        for (int j = 0; j < 2; ++j)
#pragma unroll
            for (int s = 0; s < 2; ++s)
                b[j][s] = *(const bf16x8*)(base + boff[s] + j * 2048);
        __builtin_amdgcn_s_setprio(1);
#pragma unroll
        for (int i = 0; i < 4; ++i)
#pragma unroll
            for (int j = 0; j < 2; ++j)
#pragma unroll
                for (int s = 0; s < 2; ++s)
                    acc[i][j] = __builtin_amdgcn_mfma_f32_16x16x32_bf16(
                        a[i][s], b[j][s], acc[i][j], 0, 0, 0);
        __builtin_amdgcn_s_setprio(0);
        __builtin_amdgcn_s_barrier();              // BAR#1: A region read-done (all waves)

        // ===== ph1: stage A(t+2); read b[2..3]; MFMA j=2,3; counted vmcnt; BAR#2
        if (t + 2 < T) {
#pragma unroll
            for (int g = 0; g < 4; ++g)
                gl2lds16(sA[g] + kb, smem + ((t & 1) << 15) + dA[g]);
        }
#pragma unroll
        for (int j = 2; j < 4; ++j)
#pragma unroll
            for (int s = 0; s < 2; ++s)
                b[j][s] = *(const bf16x8*)(base + boff[s] + j * 2048);
        __builtin_amdgcn_s_setprio(1);
#pragma unroll
        for (int i = 0; i < 4; ++i)
#pragma unroll
            for (int j = 2; j < 4; ++j)
#pragma unroll
                for (int s = 0; s < 2; ++s)
                    acc[i][j] = __builtin_amdgcn_mfma_f32_16x16x32_bf16(
                        a[i][s], b[j][s], acc[i][j], 0, 0, 0);
        __builtin_amdgcn_s_setprio(0);
        if (t + 2 < T) {
            asm volatile("s_waitcnt vmcnt(4)" ::: "memory");  // A(t+1),B(t+1) resident
        } else {
            asm volatile("s_waitcnt vmcnt(0)" ::: "memory");  // tail: drain everything
        }
        __builtin_amdgcn_s_barrier();              // BAR#2: B region read-done (all waves)

        // ===== ph2: stage B(t+2)  (no barrier; flows into next tile ph0)
        if (t + 2 < T) {
#pragma unroll
            for (int g = 0; g < 4; ++g)
                gl2lds16(sB[g] + kb, smem + ((t & 1) << 15) + dB[g]);
        }
    }

    // ---- epilogue: C/D layout col = lane&15, row = (lane>>4)*4 + reg
#pragma unroll
    for (int i = 0; i < 4; ++i) {
#pragma unroll
        for (int r = 0; r < 4; ++r) {
            const size_t gr = row0 + wm * 64 + i * 16 + fq * 4 + r;
#pragma unroll
            for (int j = 0; j < 4; ++j) {
                const size_t gc  = col0 + wn * 64 + j * 16 + fr;
                const size_t idx = gr * (size_t)N + gc;
                const float v = acc[i][j][r];
                if (EPI == EPI_BIAS) {
                    ((float*)outp)[idx] = v + bias[gc];
                } else if (EPI == EPI_CMB) {
                    ((u16*)outp)[idx] = f2b(v - bias[gc]);
                } else if (EPI == EPI_W) {
                    ((u16*)outp)[idx] = f2b(v);
                } else {
                    ((float*)outp)[idx] = b2f(H[idx]) + 0.2f * (b2f(Cc[idx]) - v);
                }
            }
        }
    }
}

// ---------------------------------------------------------------- host
extern "C" void kernel_launch(void* const* d_in, const int* in_sizes, int n_in,
                              void* d_out, int out_size, void* d_ws, size_t ws_size,
                              hipStream_t stream) {
    const int B = 8192;
    const float* x      = (const float*)d_in[0];
    const float* gen_w0 = (const float*)d_in[1];
    const float* gen_b0 = (const float*)d_in[2];
    const float* rec_w0 = (const float*)d_in[3];
    const float* rec_b0 = (const float*)d_in[4];
    const float* log_p0 = (const float*)d_in[5];
    const float* ln_g0  = (const float*)d_in[6];
    const float* ln_b0  = (const float*)d_in[7];
    const float* gen_w1 = (const float*)d_in[8];
    const float* gen_b1 = (const float*)d_in[9];
    const float* rec_w1 = (const float*)d_in[10];
    const float* rec_b1 = (const float*)d_in[11];
    const float* log_p1 = (const float*)d_in[12];
    const float* ln_g1  = (const float*)d_in[13];
    const float* ln_b1  = (const float*)d_in[14];

    char* ws = (char*)d_ws;
    auto alloc = [&](size_t bytes) -> char* {
        char* p = ws;
        ws += (bytes + 255) & ~(size_t)255;
        return p;
    };
    u16*   Xb   = (u16*)  alloc((size_t)B * 4096 * 2);   // x bf16; L1-prep region after c0
    float* Tf   = (float*)alloc((size_t)B * 2048 * 4);   // pre-LN fp32
    u16*   Hb0  = (u16*)  alloc((size_t)B * 2048 * 2);
    u16*   Cb0  = (u16*)  alloc((size_t)B * 2048 * 2);   // c0 bf16; Gt0 during pre-pass
    u16*   rwb0 = (u16*)  alloc((size_t)2048 * 4096 * 2);
    u16*   DGt0 = (u16*)  alloc((size_t)2048 * 4096 * 2);// Hb1 after c0
    u16*   W0   = (u16*)  alloc((size_t)2048 * 2048 * 2);
    float* p20  = (float*)alloc(4096 * 4);
    float* p21  = (float*)alloc(2048 * 4);
    float* cv0  = (float*)alloc(2048 * 4);
    float* cv1  = (float*)alloc(1024 * 4);

    u16* Gt0 = Cb0;                       // [2048,4096] fits in Cb0
    u16* Hb1 = DGt0;                      // [8192,1024] == DGt0 size
    char* l1 = (char*)Xb;
    u16* rwb1 = (u16*)l1;                 l1 += (size_t)1024 * 2048 * 2;
    u16* Gt1  = (u16*)l1;                 l1 += (size_t)1024 * 2048 * 2;
    u16* DGt1 = (u16*)l1;                 l1 += (size_t)1024 * 2048 * 2;
    u16* W1   = (u16*)l1;                 l1 += (size_t)1024 * 1024 * 2;
    u16* Cb1  = (u16*)l1;                 l1 += (size_t)B * 1024 * 2;

    auto cast = [&](const float* s, u16* d, size_t n) {
        int n4 = (int)(n >> 2);
        cast_bf16_kernel<<<dim3((n4 + 255) / 256), dim3(256), 0, stream>>>(
            (const float4*)s, (ushort4*)d, n4);
    };
    const dim3 blk(256);
    const size_t LDSG = 65536;

    // ---- pre-pass (layer 0)
    prec2_kernel<<<dim3(16), blk, 0, stream>>>(log_p0, p20, 4096);
    prec2_kernel<<<dim3(8),  blk, 0, stream>>>(log_p1, p21, 2048);
    cast(x, Xb, (size_t)B * 4096);
    cast(rec_w0, rwb0, (size_t)2048 * 4096);
    transpose_cast_kernel<<<dim3(2048 / 32, 4096 / 32), blk, 0, stream>>>(
        gen_w0, Gt0, 4096, 2048, nullptr);           // Gt0[j][i] = G0[i][j]
    transpose_cast_kernel<<<dim3(2048 / 32, 4096 / 32), blk, 0, stream>>>(
        gen_w0, DGt0, 4096, 2048, p20);              // DGt0[j][i] = p2[i]*G0[i][j]
    cvec_kernel<<<dim3(2048 / 4), blk, 0, stream>>>(gen_b0, DGt0, cv0, 4096);
    // W0 = G0^T D G0  [2048,2048] bf16 (symmetric)
    gemm128<EPI_W><<<dim3(16, 16), blk, LDSG, stream>>>(
        Gt0, DGt0, 2048, 4096, nullptr, nullptr, nullptr, W0);

    // ---- layer 0 (in=4096, hid=2048)
    gemm128<EPI_BIAS><<<dim3(16, 64), blk, LDSG, stream>>>(
        Xb, rwb0, 2048, 4096, rec_b0, nullptr, nullptr, Tf);
    ln_kernel<0><<<dim3(B), blk, 0, stream>>>(Tf, ln_g0, ln_b0, Hb0, 2048);
    // c0 = x @ (D G0) - cv0   (last use of Xb, Gt0/Cb0 free after this writes)
    gemm128<EPI_CMB><<<dim3(16, 64), blk, LDSG, stream>>>(
        Xb, DGt0, 2048, 4096, cv0, nullptr, nullptr, Cb0);

    // ---- L1 prep (overwrites Xb region; DGt0 still live until here — done)
    cast(rec_w1, rwb1, (size_t)1024 * 2048);
    transpose_cast_kernel<<<dim3(1024 / 32, 2048 / 32), blk, 0, stream>>>(
        gen_w1, Gt1, 2048, 1024, nullptr);
    transpose_cast_kernel<<<dim3(1024 / 32, 2048 / 32), blk, 0, stream>>>(
        gen_w1, DGt1, 2048, 1024, p21);
    cvec_kernel<<<dim3(1024 / 4), blk, 0, stream>>>(gen_b1, DGt1, cv1, 2048);
    gemm128<EPI_W><<<dim3(8, 8), blk, LDSG, stream>>>(
        Gt1, DGt1, 1024, 2048, nullptr, nullptr, nullptr, W1);

    // ---- layer 0 iterations: T = h + 0.2*(c0 - h@W0); h = LN(T)
    for (int it = 0; it < 3; ++it) {
        gemm128<EPI_ITER><<<dim3(16, 64), blk, LDSG, stream>>>(
            Hb0, W0, 2048, 2048, nullptr, Cb0, Hb0, Tf);
        ln_kernel<0><<<dim3(B), blk, 0, stream>>>(Tf, ln_g0, ln_b0, Hb0, 2048);
    }

    // ---- layer 1 (in=2048, hid=1024); input = Hb0 (bf16)
    gemm128<EPI_BIAS><<<dim3(8, 64), blk, LDSG, stream>>>(
        Hb0, rwb1, 1024, 2048, rec_b1, nullptr, nullptr, Tf);
    ln_kernel<0><<<dim3(B), blk, 0, stream>>>(Tf, ln_g1, ln_b1, Hb1, 1024);
    gemm128<EPI_CMB><<<dim3(8, 64), blk, LDSG, stream>>>(
        Hb0, DGt1, 1024, 2048, cv1, nullptr, nullptr, Cb1);
    for (int it = 0; it < 3; ++it) {
        gemm128<EPI_ITER><<<dim3(8, 64), blk, LDSG, stream>>>(
            Hb1, W1, 1024, 1024, nullptr, Cb1, Hb1, Tf);
        if (it < 2)
            ln_kernel<0><<<dim3(B), blk, 0, stream>>>(Tf, ln_g1, ln_b1, Hb1, 1024);
        else
            ln_kernel<1><<<dim3(B), blk, 0, stream>>>(Tf, ln_g1, ln_b1, d_out, 1024);
    }
}